// Round 13
// baseline (259.845 us; speedup 1.0000x reference)
//
#include <hip/hip_runtime.h>
#include <hip/hip_cooperative_groups.h>
#include <stdint.h>

namespace cg = cooperative_groups;

typedef unsigned long long u64;
typedef unsigned int u32;

#define BB 4
#define NN 321408
#define K_PRE 1000
#define K_POST 300
#define CAP 4096
#define NW 16                 // 1000 bits -> 16 u64 words
#define SCORE_THR 0.05f
#define IOU_THR 0.5f
#define SB 314                // slice blocks per batch (ceil(NN/1024))
#define CH2 1024              // anchors per slice block
#define NBINS 576             // 16-bit key prefixes span 0xBD4C..0xBF80 (s in [0.05,1.0])
#define BIN0 0xBD4Cu
#define RED 8                 // wide 2-stage reduce (NEVER 4-block serial — R7/R11 lesson)
#define RCH 40
#define GRID 256              // cooperative grid: 1 block/CU, co-residency guaranteed
#define TPB 256

__device__ __forceinline__ float sigm(float x) { return 1.0f / (1.0f + expf(-x)); }

__device__ __forceinline__ u32 mkkey(float mx) {
    float s = sigm(mx);
    return (s >= SCORE_THR) ? (__float_as_uint(s) | 0x80000000u) : 0u;
}

// ---------------- shared-memory union for the mega kernel ----------------
struct P1s { u32 h1[NBINS]; u32 h2[NBINS]; };
struct P3s { u32 tot[NBINS]; u32 wt[4]; u32 sT; u32 starg; };
struct P4s { u32 wtot[4]; };
struct P5s { u64 ck[CAP]; };
struct P6s { float s4[(K_PRE + 16) * 4]; float sA[K_PRE + 16]; };
struct P7s { u64 km[16]; int sel[K_POST]; int cnt_s; };
union SmemU { P1s p1; P3s p3; P4s p4; P5s p5; P6s p6; P7s p7; };

// ================= MEGA: whole pipeline, one cooperative dispatch =================
__global__ void __launch_bounds__(TPB) k_mega(const float* __restrict__ boxp, const float* __restrict__ cls,
                                              const float* __restrict__ dirp, const float* __restrict__ anch,
                                              float* __restrict__ out, char* __restrict__ ws) {
    __shared__ SmemU sm;
    cg::grid_group gg = cg::this_grid();
    int bid = blockIdx.x, tid = threadIdx.x;
    int lane = tid & 63, wv = tid >> 6;

    char* p = ws;
    u32* key  = (u32*)p; p += (size_t)BB * NN * 4;
    u32* bh   = (u32*)p; p += (size_t)BB * SB * NBINS * 4;
    u32* part = (u32*)p; p += (size_t)BB * RED * NBINS * 4;
    u32* cnt  = (u32*)p; p += 256;
    u32* thr  = (u32*)p; p += 256;
    u32* boff = (u32*)p; p += (size_t)BB * SB * 4 + 256;
    u64* cand = (u64*)p; p += (size_t)BB * CAP * 8;
    float* tks = (float*)p; p += (size_t)BB * K_PRE * 4;
    u32* meta = (u32*)p; p += (size_t)BB * K_PRE * 4;
    float* box7 = (float*)p; p += (size_t)BB * K_PRE * 7 * 4;
    float* cor  = (float*)p; p += (size_t)BB * K_PRE * 5 * 4;
    u64* maskT = (u64*)p;

    // ---- Phase 1: keys + 576-bin suffix-cumulative hist per slice ----
    for (int task = bid; task < BB * SB; task += GRID) {
        int b = task / SB, c = task % SB;
        for (int i = tid; i < NBINS; i += TPB) sm.p1.h1[i] = 0;
        __syncthreads();
        int a0 = c * CH2 + tid * 4;
        if (a0 < NN) {
            const float4* c4 = (const float4*)(cls + ((size_t)b * NN + a0) * 3);
            float4 v0 = c4[0], v1 = c4[1], v2 = c4[2];
            uint4 o;
            o.x = mkkey(fmaxf(v0.x, fmaxf(v0.y, v0.z)));
            o.y = mkkey(fmaxf(v0.w, fmaxf(v1.x, v1.y)));
            o.z = mkkey(fmaxf(v1.z, fmaxf(v1.w, v2.x)));
            o.w = mkkey(fmaxf(v2.y, fmaxf(v2.z, v2.w)));
            *((uint4*)(key + (size_t)b * NN + a0)) = o;
            if (o.x) atomicAdd(&sm.p1.h1[min((o.x >> 16) - BIN0, (u32)(NBINS - 1))], 1u);
            if (o.y) atomicAdd(&sm.p1.h1[min((o.y >> 16) - BIN0, (u32)(NBINS - 1))], 1u);
            if (o.z) atomicAdd(&sm.p1.h1[min((o.z >> 16) - BIN0, (u32)(NBINS - 1))], 1u);
            if (o.w) atomicAdd(&sm.p1.h1[min((o.w >> 16) - BIN0, (u32)(NBINS - 1))], 1u);
        }
        __syncthreads();
        u32* src = sm.p1.h1; u32* dst = sm.p1.h2;
        for (int off = 1; off < NBINS; off <<= 1) {       // 10-pass suffix scan
            for (int i = tid; i < NBINS; i += TPB)
                dst[i] = src[i] + ((i + off < NBINS) ? src[i + off] : 0u);
            __syncthreads();
            u32* t = src; src = dst; dst = t;
        }
        for (int i = tid; i < NBINS; i += TPB) bh[(size_t)task * NBINS + i] = src[i];
        __syncthreads();
    }
    gg.sync();

    // ---- Phase 2: wide column-sum of slice hists -> partials (96 blocks active) ----
    if (bid < BB * RED * 3) {
        int b = bid / (RED * 3), r = (bid / 3) % RED, g = bid % 3;
        int f = g * 256 + tid;
        if (f < NBINS) {
            int s0 = r * RCH, s1 = s0 + RCH; if (s1 > SB) s1 = SB;
            const u32* base = bh + (size_t)(b * SB + s0) * NBINS + f;
            u32 acc = 0; int n = s1 - s0;
            #pragma unroll 8
            for (int s = 0; s < n; ++s) acc += base[(size_t)s * NBINS];
            part[(size_t)(b * RED + r) * NBINS + f] = acc;
        }
    }
    gg.sync();

    // ---- Phase 3: threshold crossing + per-slice counts + prefix scan (4 blocks) ----
    if (bid < BB) {
        int b = bid;
        for (int f = tid; f < NBINS; f += TPB) {
            u32 x = 0;
            #pragma unroll
            for (int r = 0; r < RED; ++r) x += part[(size_t)(b * RED + r) * NBINS + f];
            sm.p3.tot[f] = x;
        }
        __syncthreads();
        if (tid == 0) {
            u32 tv = sm.p3.tot[0];
            sm.p3.starg = (tv < K_PRE) ? tv : K_PRE;
            if (sm.p3.starg == 0) { sm.p3.sT = 0x10000u; thr[b] = 0x10000u; }
        }
        __syncthreads();
        u32 target = sm.p3.starg;
        if (target > 0) {
            for (int f = tid; f < NBINS; f += TPB) {       // tot non-increasing -> unique crossing
                u32 cge = sm.p3.tot[f];
                u32 cnx = (f + 1 < NBINS) ? sm.p3.tot[f + 1] : 0u;
                if (cge >= target && cnx < target) { sm.p3.sT = BIN0 + (u32)f; thr[b] = BIN0 + (u32)f; }
            }
        }
        __syncthreads();
        u32 T = sm.p3.sT;
        u32 vA = 0, vB = 0;
        if (target > 0) {
            if (tid < SB) vA = bh[(size_t)(b * SB + tid) * NBINS + (T - BIN0)];
            if (tid + 256 < SB) vB = bh[(size_t)(b * SB + tid + 256) * NBINS + (T - BIN0)];
        }
        u32 x = vA;                                        // scan slices 0..255
        #pragma unroll
        for (int o = 1; o < 64; o <<= 1) { u32 y = __shfl_up(x, o); if (lane >= o) x += y; }
        if (lane == 63) sm.p3.wt[wv] = x;
        __syncthreads();
        u32 preA = 0, totA;
        { u32 w0 = sm.p3.wt[0], w1 = sm.p3.wt[1], w2 = sm.p3.wt[2], w3 = sm.p3.wt[3];
          if (wv > 0) preA += w0; if (wv > 1) preA += w1; if (wv > 2) preA += w2;
          totA = w0 + w1 + w2 + w3; }
        __syncthreads();
        u32 xb = vB;                                       // scan slices 256..313
        #pragma unroll
        for (int o = 1; o < 64; o <<= 1) { u32 y = __shfl_up(xb, o); if (lane >= o) xb += y; }
        if (lane == 63) sm.p3.wt[wv] = xb;
        __syncthreads();
        u32 preB = 0, totB;
        { u32 w0 = sm.p3.wt[0], w1 = sm.p3.wt[1], w2 = sm.p3.wt[2], w3 = sm.p3.wt[3];
          if (wv > 0) preB += w0; if (wv > 1) preB += w1; if (wv > 2) preB += w2;
          totB = w0 + w1 + w2 + w3; }
        if (tid < SB) boff[b * SB + tid] = preA + x - vA;
        if (tid + 256 < SB) boff[b * SB + tid + 256] = totA + preB + xb - vB;
        if (tid == 0) cnt[b] = totA + totB;
    }
    gg.sync();

    // ---- Phase 4: scatter candidates at prefix offsets ----
    for (int task = bid; task < BB * SB; task += GRID) {
        int b = task / SB, c = task % SB;
        u32 T = thr[b];
        int a0 = c * CH2 + tid * 4;
        uint4 kk = make_uint4(0u, 0u, 0u, 0u);
        if (a0 < NN) kk = *((const uint4*)(key + (size_t)b * NN + a0));
        u32 ks[4] = {kk.x, kk.y, kk.z, kk.w};
        u32 f[4];
        #pragma unroll
        for (int e = 0; e < 4; ++e) f[e] = (u32)((ks[e] != 0) && ((ks[e] >> 16) >= T));
        u32 tc = f[0] + f[1] + f[2] + f[3];
        u32 x = tc;
        #pragma unroll
        for (int o = 1; o < 64; o <<= 1) { u32 y = __shfl_up(x, o); if (lane >= o) x += y; }
        if (lane == 63) sm.p4.wtot[wv] = x;
        __syncthreads();
        u32 base = 0;
        { u32 w0 = sm.p4.wtot[0], w1 = sm.p4.wtot[1], w2 = sm.p4.wtot[2];
          if (wv > 0) base += w0; if (wv > 1) base += w1; if (wv > 2) base += w2; }
        u32 pos = boff[task] + base + x - tc;
        u64* cb = cand + (size_t)b * CAP;
        #pragma unroll
        for (int e = 0; e < 4; ++e) {
            if (f[e]) {                                    // candidate SET; order irrelevant
                if (pos < CAP) cb[pos] = ((u64)(~ks[e]) << 32) | (u64)(a0 + e);
                ++pos;
            }
        }
        __syncthreads();
    }
    gg.sync();

    // ---- Phase 5: rank (64 cand/block, 1-wave LDS-broadcast scan) + decode ----
    {
        int b = bid >> 6, g = bid & 63;                    // 256 blocks exactly
        u32 nc = cnt[b]; if (nc > CAP) nc = CAP;
        int ci0 = g * 64;
        bool active = (ci0 < (int)nc) || (ci0 < K_PRE);    // block-uniform
        if (active) {
            const u64* cb = cand + (size_t)b * CAP;
            for (int i = tid; i < (int)nc; i += TPB) sm.p5.ck[i] = cb[i];
            __syncthreads();
            int rank = -1; u32 idx = 0xFFFFFFFFu;
            if (tid < 64) {
                int ci = ci0 + tid;
                if (ci < (int)nc) {
                    u64 my = sm.p5.ck[ci];
                    u32 r = 0;
                    int j = 0, nlim = (int)nc & ~15;
                    for (; j < nlim; j += 16) {            // 16 uniform broadcast reads in flight
                        u64 v0 = sm.p5.ck[j+0], v1 = sm.p5.ck[j+1], v2 = sm.p5.ck[j+2], v3 = sm.p5.ck[j+3];
                        u64 v4 = sm.p5.ck[j+4], v5 = sm.p5.ck[j+5], v6 = sm.p5.ck[j+6], v7 = sm.p5.ck[j+7];
                        u64 v8 = sm.p5.ck[j+8], v9 = sm.p5.ck[j+9], va = sm.p5.ck[j+10], vb = sm.p5.ck[j+11];
                        u64 vc = sm.p5.ck[j+12], vd = sm.p5.ck[j+13], ve = sm.p5.ck[j+14], vf = sm.p5.ck[j+15];
                        r += (u32)(v0 < my) + (u32)(v1 < my) + (u32)(v2 < my) + (u32)(v3 < my)
                           + (u32)(v4 < my) + (u32)(v5 < my) + (u32)(v6 < my) + (u32)(v7 < my)
                           + (u32)(v8 < my) + (u32)(v9 < my) + (u32)(va < my) + (u32)(vb < my)
                           + (u32)(vc < my) + (u32)(vd < my) + (u32)(ve < my) + (u32)(vf < my);
                    }
                    for (; j < (int)nc; ++j) r += (u32)(sm.p5.ck[j] < my);
                    if (r < K_PRE) { rank = (int)r; idx = (u32)my; }
                } else if (ci < K_PRE) {
                    rank = ci;                             // filler (disjoint from real ranks)
                }
            }
            if (rank >= 0) {
                float ob[7] = {0,0,0,0,0,0,0};
                float c5[5] = {0,0,0,0,0};
                float sc = 0.f; u32 mt = 0;
                if (idx != 0xFFFFFFFFu) {
                    const float* A = anch + (size_t)idx * 7;
                    const float* D = boxp + ((size_t)b * NN + idx) * 7;
                    float xa=A[0], ya=A[1], za=A[2], wa=A[3], la=A[4], ha=A[5], ra=A[6];
                    float xt=D[0], yt=D[1], zt=D[2], wt2=D[3], lt=D[4], ht=D[5], rt=D[6];
                    za = za + ha * 0.5f;
                    float diag = sqrtf(la * la + wa * wa);
                    float xg = xt * diag + xa;
                    float yg = yt * diag + ya;
                    float zg = zt * ha + za;
                    float wg = expf(wt2) * wa;
                    float lg = expf(lt) * la;
                    float hg = expf(ht) * ha;
                    zg = zg - hg * 0.5f;
                    float rg = rt + ra;
                    ob[0]=xg; ob[1]=yg; ob[2]=zg; ob[3]=wg; ob[4]=lg; ob[5]=hg; ob[6]=rg;
                    float cr = fabsf(cosf(rg)), sr = fabsf(sinf(rg));
                    float hx = 0.5f * (wg * cr + lg * sr);
                    float hy = 0.5f * (wg * sr + lg * cr);
                    float x1 = xg - hx, x2 = xg + hx, y1 = yg - hy, y2 = yg + hy;
                    c5[0]=x1; c5[1]=x2; c5[2]=y1; c5[3]=y2; c5[4]=(x2-x1)*(y2-y1);
                    const float* cc = cls + ((size_t)b * NN + idx) * 3;
                    float p0 = sigm(cc[0]), p1 = sigm(cc[1]), p2 = sigm(cc[2]);
                    int lbl = 0; float best = p0;
                    if (p1 > best) { best = p1; lbl = 1; }
                    if (p2 > best) { best = p2; lbl = 2; }
                    sc = best;
                    const float* dd = dirp + ((size_t)b * NN + idx) * 2;
                    int dl = (dd[1] > dd[0]) ? 1 : 0;
                    mt = (u32)lbl | ((u32)dl << 8) | (1u << 16);
                }
                size_t t = (size_t)b * K_PRE + rank;
                tks[t] = sc; meta[t] = mt;
                #pragma unroll
                for (int j = 0; j < 7; ++j) box7[t * 7 + j] = ob[j];
                #pragma unroll
                for (int j = 0; j < 5; ++j) cor[t * 5 + j] = c5[j];
            }
        }
    }
    gg.sync();

    // ---- Phase 6: transposed suppression bitmask (252 blocks active) ----
    if (bid < BB * 63) {
        int b = bid / 63, jb = bid % 63;
        const float4* C4 = (const float4*)(cor + (size_t)b * K_PRE * 5);
        for (int q = tid; q < (K_PRE * 5) / 4; q += TPB) {
            float4 v = C4[q];
            int t0 = q * 4;
            #pragma unroll
            for (int e = 0; e < 4; ++e) {
                int t = t0 + e;
                int i = t / 5, k = t - i * 5;
                float val = (e == 0) ? v.x : (e == 1) ? v.y : (e == 2) ? v.z : v.w;
                int ip = i + (i >> 6);
                if (k < 4) sm.p6.s4[ip * 4 + k] = val; else sm.p6.sA[ip] = val;
            }
        }
        __syncthreads();
        int w = tid & 15, jl = tid >> 4;
        int j = jb * 16 + jl;
        if (j < K_PRE) {
            int jp = j + (j >> 6);
            float x1 = sm.p6.s4[jp*4+0], x2 = sm.p6.s4[jp*4+1];
            float y1 = sm.p6.s4[jp*4+2], y2 = sm.p6.s4[jp*4+3], ar = sm.p6.sA[jp];
            u64 m = 0;
            int i0 = w * 64;
            if (i0 < j) {
                int iend = j - i0; if (iend > 64) iend = 64;
                for (int ii = 0; ii < iend; ++ii) {
                    int i = i0 + ii;
                    int ip = i + (i >> 6);
                    float4 bx = *(const float4*)&sm.p6.s4[ip * 4];
                    float ai = sm.p6.sA[ip];
                    float ix = fminf(x2, bx.y) - fmaxf(x1, bx.x); ix = fmaxf(ix, 0.f);
                    float iy = fminf(y2, bx.w) - fmaxf(y1, bx.z); iy = fmaxf(iy, 0.f);
                    float inter = ix * iy;
                    float uni = ai + ar - inter;
                    float iou = (uni > 0.f) ? inter / fmaxf(uni, 1e-12f) : 0.f;
                    if (iou > IOU_THR) m |= (1ull << ii);
                }
            }
            maskT[((size_t)b * K_PRE + j) * NW + w] = m;
        }
    }
    gg.sync();

    // ---- Phase 7: greedy NMS over kept boxes + outputs (4 blocks) ----
    if (bid < BB) {
        int b = bid;
        if (tid < 16) sm.p7.km[tid] = 0ull;
        __syncthreads();
        if (tid < 64) {
            int c2 = 0; bool done = false;
            const u32* M = meta + b * K_PRE;
            for (int c = 0; c < 16; ++c) {
                if (done) break;
                int j = c * 64 + lane;
                int jc = (j < K_PRE) ? j : (K_PRE - 1);
                bool jvalid = (j < K_PRE) && ((M[jc] >> 16) & 1u);
                const u64* colp = maskT + ((size_t)b * K_PRE + jc) * NW;
                u64 cw = 0; u64 supacc = 0;
                #pragma unroll
                for (int w = 0; w < 16; ++w) {
                    u64 cv = colp[w];
                    supacc |= (cv & sm.p7.km[w]);
                    if (w == c) cw = cv;
                }
                u64 active2 = __ballot(jvalid && (supacc == 0ull));
                u64 kmc = 0;
                while (active2) {
                    int i = __ffsll((unsigned long long)active2) - 1;
                    if (lane == 0) sm.p7.sel[c2] = c * 64 + i;
                    ++c2;
                    if (c2 >= K_POST) { done = true; break; }
                    kmc |= (1ull << i);
                    u64 supb = __ballot(((cw >> i) & 1ull) != 0ull);
                    active2 &= ~supb;
                    active2 &= ~(1ull << i);
                }
                if (lane == 0) sm.p7.km[c] = kmc;
            }
            if (lane == 0) sm.p7.cnt_s = c2;
        }
        __syncthreads();
        int kept = sm.p7.cnt_s;
        const u32* M = meta + b * K_PRE;
        const float* BX = box7 + (size_t)b * K_PRE * 7;
        const float* SS = tks + b * K_PRE;
        for (int pp = tid; pp < K_POST; pp += TPB) {
            float ob[7] = {0,0,0,0,0,0,0};
            float sc = 0.f, lb = 0.f, vd = 0.f;
            if (pp < kept) {
                int i = sm.p7.sel[pp];
                float xg = BX[i*7+0], yg = BX[i*7+1], zg = BX[i*7+2];
                bool in_range = (xg >= 0.0f) && (xg <= 69.12f) &&
                                (yg >= -39.68f) && (yg <= 39.68f) &&
                                (zg >= -5.0f) && (zg <= 5.0f);
                if (in_range) {
                    u32 mt = M[i];
                    int dl = (mt >> 8) & 0xFF;
                    float r = BX[i*7+6];
                    bool opp = ((r > 0.0f) != (dl == 1));
                    float rf = r + (opp ? 3.14159274f : 0.0f);
                    ob[0]=xg; ob[1]=yg; ob[2]=zg; ob[3]=BX[i*7+3]; ob[4]=BX[i*7+4]; ob[5]=BX[i*7+5]; ob[6]=rf;
                    sc = SS[i]; lb = (float)(mt & 0xFF); vd = 1.0f;
                }
            }
            size_t ro = (size_t)(b * K_POST + pp);
            #pragma unroll
            for (int j = 0; j < 7; ++j) out[ro * 7 + j] = ob[j];
            out[(size_t)BB * K_POST * 7 + ro] = lb;
            out[(size_t)BB * K_POST * 8 + ro] = sc;
            out[(size_t)BB * K_POST * 9 + ro] = vd;
        }
    }
}

// ================= FALLBACK: proven R12 7-kernel pipeline =================
__global__ void k_score_hist(const float* __restrict__ cls, u32* __restrict__ key, u32* __restrict__ bh) {
    __shared__ u32 h1[NBINS], h2[NBINS];
    int bb = blockIdx.x, tid = threadIdx.x;
    int b = bb / SB, c = bb % SB;
    for (int i = tid; i < NBINS; i += 256) h1[i] = 0;
    __syncthreads();
    int a0 = c * CH2 + tid * 4;
    if (a0 < NN) {
        const float4* c4 = (const float4*)(cls + ((size_t)b * NN + a0) * 3);
        float4 v0 = c4[0], v1 = c4[1], v2 = c4[2];
        uint4 o;
        o.x = mkkey(fmaxf(v0.x, fmaxf(v0.y, v0.z)));
        o.y = mkkey(fmaxf(v0.w, fmaxf(v1.x, v1.y)));
        o.z = mkkey(fmaxf(v1.z, fmaxf(v1.w, v2.x)));
        o.w = mkkey(fmaxf(v2.y, fmaxf(v2.z, v2.w)));
        *((uint4*)(key + (size_t)b * NN + a0)) = o;
        if (o.x) atomicAdd(&h1[min((o.x >> 16) - BIN0, (u32)(NBINS - 1))], 1u);
        if (o.y) atomicAdd(&h1[min((o.y >> 16) - BIN0, (u32)(NBINS - 1))], 1u);
        if (o.z) atomicAdd(&h1[min((o.z >> 16) - BIN0, (u32)(NBINS - 1))], 1u);
        if (o.w) atomicAdd(&h1[min((o.w >> 16) - BIN0, (u32)(NBINS - 1))], 1u);
    }
    __syncthreads();
    u32* src = h1; u32* dst = h2;
    for (int off = 1; off < NBINS; off <<= 1) {
        for (int i = tid; i < NBINS; i += 256)
            dst[i] = src[i] + ((i + off < NBINS) ? src[i + off] : 0u);
        __syncthreads();
        u32* t = src; src = dst; dst = t;
    }
    for (int i = tid; i < NBINS; i += 256) bh[(size_t)bb * NBINS + i] = src[i];
}

__global__ __launch_bounds__(64) void k_red(const u32* __restrict__ bh, u32* __restrict__ part) {
    int blk = blockIdx.x, tid = threadIdx.x;
    int b = blk / (RED * 9); int r = (blk / 9) % RED; int g = blk % 9;
    int f = g * 64 + tid;
    int s0 = r * RCH, s1 = s0 + RCH; if (s1 > SB) s1 = SB;
    const u32* base = bh + (size_t)(b * SB + s0) * NBINS + f;
    u32 acc = 0; int n = s1 - s0;
    #pragma unroll 8
    for (int s = 0; s < n; ++s) acc += base[(size_t)s * NBINS];
    part[(size_t)(b * RED + r) * NBINS + f] = acc;
}

__global__ __launch_bounds__(512) void k_scanoff(const u32* __restrict__ part, const u32* __restrict__ bh,
                                                 u32* __restrict__ thr, u32* __restrict__ boff,
                                                 u32* __restrict__ cnt) {
    __shared__ u32 tot[NBINS];
    __shared__ u32 wt[8];
    __shared__ u32 sT, starg;
    int b = blockIdx.x, tid = threadIdx.x;
    for (int f = tid; f < NBINS; f += 512) {
        u32 x = 0;
        #pragma unroll
        for (int r = 0; r < RED; ++r) x += part[(size_t)(b * RED + r) * NBINS + f];
        tot[f] = x;
    }
    __syncthreads();
    if (tid == 0) {
        u32 tv = tot[0];
        starg = (tv < K_PRE) ? tv : K_PRE;
        if (starg == 0) { sT = 0x10000u; thr[b] = 0x10000u; }
    }
    __syncthreads();
    u32 target = starg;
    if (target > 0) {
        for (int f = tid; f < NBINS; f += 512) {
            u32 cge = tot[f];
            u32 cnx = (f + 1 < NBINS) ? tot[f + 1] : 0u;
            if (cge >= target && cnx < target) { sT = BIN0 + (u32)f; thr[b] = BIN0 + (u32)f; }
        }
    }
    __syncthreads();
    u32 v = 0;
    if (target > 0 && tid < SB) v = bh[(size_t)(b * SB + tid) * NBINS + (sT - BIN0)];
    int lane = tid & 63, wv = tid >> 6;
    u32 x = v;
    #pragma unroll
    for (int o = 1; o < 64; o <<= 1) { u32 y = __shfl_up(x, o); if (lane >= o) x += y; }
    if (lane == 63) wt[wv] = x;
    __syncthreads();
    u32 pre = 0;
    #pragma unroll
    for (int w = 0; w < 7; ++w) pre += (w < wv) ? wt[w] : 0u;
    if (tid < SB) boff[b * SB + tid] = pre + x - v;
    if (tid == 511) cnt[b] = pre + x;
}

__global__ void k_scatter(const u32* __restrict__ key, const u32* __restrict__ thr,
                          const u32* __restrict__ boff, u64* __restrict__ cand) {
    __shared__ u32 wtot[4];
    int bb = blockIdx.x, tid = threadIdx.x;
    int b = bb / SB, c = bb % SB;
    u32 T = thr[b];
    int a0 = c * CH2 + tid * 4;
    uint4 kk = make_uint4(0u, 0u, 0u, 0u);
    if (a0 < NN) kk = *((const uint4*)(key + (size_t)b * NN + a0));
    u32 ks[4] = {kk.x, kk.y, kk.z, kk.w};
    u32 f[4];
    #pragma unroll
    for (int e = 0; e < 4; ++e) f[e] = (u32)((ks[e] != 0) && ((ks[e] >> 16) >= T));
    u32 tc = f[0] + f[1] + f[2] + f[3];
    int lane = tid & 63, wv = tid >> 6;
    u32 x = tc;
    #pragma unroll
    for (int o = 1; o < 64; o <<= 1) { u32 y = __shfl_up(x, o); if (lane >= o) x += y; }
    if (lane == 63) wtot[wv] = x;
    __syncthreads();
    u32 base = 0;
    u32 w0 = wtot[0], w1 = wtot[1], w2 = wtot[2];
    if (wv > 0) base += w0;
    if (wv > 1) base += w1;
    if (wv > 2) base += w2;
    u32 pos = boff[bb] + base + x - tc;
    u64* cb = cand + (size_t)b * CAP;
    #pragma unroll
    for (int e = 0; e < 4; ++e) {
        if (f[e]) {
            if (pos < CAP) cb[pos] = ((u64)(~ks[e]) << 32) | (u64)(a0 + e);
            ++pos;
        }
    }
}

__global__ __launch_bounds__(256) void k_rankdec(const u32* __restrict__ cnt, const u64* __restrict__ cand,
                                                 const float* __restrict__ boxp, const float* __restrict__ cls,
                                                 const float* __restrict__ dirp, const float* __restrict__ anch,
                                                 float* __restrict__ tks, u32* __restrict__ meta,
                                                 float* __restrict__ box7, float* __restrict__ cor) {
    __shared__ u64 ck[CAP];
    int blk = blockIdx.x, tid = threadIdx.x;
    int b = blk >> 4, rb = blk & 15;
    u32 nc = cnt[b]; if (nc > CAP) nc = CAP;
    int ci = rb * 256 + tid;
    if (rb * 256 >= (int)nc && rb * 256 >= K_PRE) return;
    const u64* cb = cand + (size_t)b * CAP;
    for (int i = tid; i < (int)nc; i += 256) ck[i] = cb[i];
    __syncthreads();
    int rank = -1; u32 idx = 0xFFFFFFFFu;
    if (ci < (int)nc) {
        u64 my = ck[ci];
        u32 r = 0;
        int j = 0, nlim = (int)nc & ~15;
        for (; j < nlim; j += 16) {
            u64 v0 = ck[j+0], v1 = ck[j+1], v2 = ck[j+2], v3 = ck[j+3];
            u64 v4 = ck[j+4], v5 = ck[j+5], v6 = ck[j+6], v7 = ck[j+7];
            u64 v8 = ck[j+8], v9 = ck[j+9], va = ck[j+10], vb = ck[j+11];
            u64 vc = ck[j+12], vd = ck[j+13], ve = ck[j+14], vf = ck[j+15];
            r += (u32)(v0 < my) + (u32)(v1 < my) + (u32)(v2 < my) + (u32)(v3 < my)
               + (u32)(v4 < my) + (u32)(v5 < my) + (u32)(v6 < my) + (u32)(v7 < my)
               + (u32)(v8 < my) + (u32)(v9 < my) + (u32)(va < my) + (u32)(vb < my)
               + (u32)(vc < my) + (u32)(vd < my) + (u32)(ve < my) + (u32)(vf < my);
        }
        for (; j < (int)nc; ++j) r += (u32)(ck[j] < my);
        if (r < K_PRE) { rank = (int)r; idx = (u32)my; }
    } else if (ci < K_PRE) {
        rank = ci;
    }
    if (rank < 0) return;
    float ob[7] = {0,0,0,0,0,0,0};
    float c5[5] = {0,0,0,0,0};
    float sc = 0.f; u32 mt = 0;
    if (idx != 0xFFFFFFFFu) {
        const float* A = anch + (size_t)idx * 7;
        const float* D = boxp + ((size_t)b * NN + idx) * 7;
        float xa=A[0], ya=A[1], za=A[2], wa=A[3], la=A[4], ha=A[5], ra=A[6];
        float xt=D[0], yt=D[1], zt=D[2], wt=D[3], lt=D[4], ht=D[5], rt=D[6];
        za = za + ha * 0.5f;
        float diag = sqrtf(la * la + wa * wa);
        float xg = xt * diag + xa;
        float yg = yt * diag + ya;
        float zg = zt * ha + za;
        float wg = expf(wt) * wa;
        float lg = expf(lt) * la;
        float hg = expf(ht) * ha;
        zg = zg - hg * 0.5f;
        float rg = rt + ra;
        ob[0]=xg; ob[1]=yg; ob[2]=zg; ob[3]=wg; ob[4]=lg; ob[5]=hg; ob[6]=rg;
        float cr = fabsf(cosf(rg)), sr = fabsf(sinf(rg));
        float hx = 0.5f * (wg * cr + lg * sr);
        float hy = 0.5f * (wg * sr + lg * cr);
        float x1 = xg - hx, x2 = xg + hx, y1 = yg - hy, y2 = yg + hy;
        c5[0]=x1; c5[1]=x2; c5[2]=y1; c5[3]=y2; c5[4]=(x2-x1)*(y2-y1);
        const float* cc = cls + ((size_t)b * NN + idx) * 3;
        float p0 = sigm(cc[0]), p1 = sigm(cc[1]), p2 = sigm(cc[2]);
        int lbl = 0; float best = p0;
        if (p1 > best) { best = p1; lbl = 1; }
        if (p2 > best) { best = p2; lbl = 2; }
        sc = best;
        const float* dd = dirp + ((size_t)b * NN + idx) * 2;
        int dl = (dd[1] > dd[0]) ? 1 : 0;
        mt = (u32)lbl | ((u32)dl << 8) | (1u << 16);
    }
    size_t t = (size_t)b * K_PRE + rank;
    tks[t] = sc; meta[t] = mt;
    #pragma unroll
    for (int j = 0; j < 7; ++j) box7[t * 7 + j] = ob[j];
    #pragma unroll
    for (int j = 0; j < 5; ++j) cor[t * 5 + j] = c5[j];
}

__global__ __launch_bounds__(256) void k_maskT(const float* __restrict__ cor, u64* __restrict__ maskT) {
    __shared__ float s4[(K_PRE + 16) * 4];
    __shared__ float sA[K_PRE + 16];
    int blk = blockIdx.x;
    int b = blk / 63, jb = blk % 63;
    int tid = threadIdx.x;
    const float4* C4 = (const float4*)(cor + (size_t)b * K_PRE * 5);
    for (int q = tid; q < (K_PRE * 5) / 4; q += 256) {
        float4 v = C4[q];
        int t0 = q * 4;
        #pragma unroll
        for (int e = 0; e < 4; ++e) {
            int t = t0 + e;
            int i = t / 5, k = t - i * 5;
            float val = (e == 0) ? v.x : (e == 1) ? v.y : (e == 2) ? v.z : v.w;
            int ip = i + (i >> 6);
            if (k < 4) s4[ip * 4 + k] = val; else sA[ip] = val;
        }
    }
    __syncthreads();
    int w = tid & 15, jl = tid >> 4;
    int j = jb * 16 + jl;
    if (j >= K_PRE) return;
    int jp = j + (j >> 6);
    float x1 = s4[jp*4+0], x2 = s4[jp*4+1], y1 = s4[jp*4+2], y2 = s4[jp*4+3], ar = sA[jp];
    u64 m = 0;
    int i0 = w * 64;
    if (i0 < j) {
        int iend = j - i0; if (iend > 64) iend = 64;
        for (int ii = 0; ii < iend; ++ii) {
            int i = i0 + ii;
            int ip = i + (i >> 6);
            float4 bx = *(const float4*)&s4[ip * 4];
            float ai = sA[ip];
            float ix = fminf(x2, bx.y) - fmaxf(x1, bx.x); ix = fmaxf(ix, 0.f);
            float iy = fminf(y2, bx.w) - fmaxf(y1, bx.z); iy = fmaxf(iy, 0.f);
            float inter = ix * iy;
            float uni = ai + ar - inter;
            float iou = (uni > 0.f) ? inter / fmaxf(uni, 1e-12f) : 0.f;
            if (iou > IOU_THR) m |= (1ull << ii);
        }
    }
    maskT[((size_t)b * K_PRE + j) * NW + w] = m;
}

__global__ __launch_bounds__(256) void k_nms_out(const u32* __restrict__ meta, const float* __restrict__ box7,
                                                 const float* __restrict__ tks, const u64* __restrict__ maskT,
                                                 float* __restrict__ out) {
    int b = blockIdx.x; int tid = threadIdx.x;
    __shared__ u64 km_s[16];
    __shared__ int sel_s[K_POST];
    __shared__ int cnt_s;
    if (tid < 16) km_s[tid] = 0ull;
    __syncthreads();
    if (tid < 64) {
        int lane = tid;
        const u32* M = meta + b * K_PRE;
        int cnt = 0; bool done = false;
        for (int c = 0; c < 16; ++c) {
            if (done) break;
            int j = c * 64 + lane;
            int jc = (j < K_PRE) ? j : (K_PRE - 1);
            bool jvalid = (j < K_PRE) && ((M[jc] >> 16) & 1u);
            const u64* colp = maskT + ((size_t)b * K_PRE + jc) * NW;
            u64 cw = 0; u64 supacc = 0;
            #pragma unroll
            for (int w = 0; w < 16; ++w) {
                u64 cv = colp[w];
                supacc |= (cv & km_s[w]);
                if (w == c) cw = cv;
            }
            u64 active = __ballot(jvalid && (supacc == 0ull));
            u64 kmc = 0;
            while (active) {
                int i = __ffsll((unsigned long long)active) - 1;
                if (lane == 0) sel_s[cnt] = c * 64 + i;
                ++cnt;
                if (cnt >= K_POST) { done = true; break; }
                kmc |= (1ull << i);
                u64 supb = __ballot(((cw >> i) & 1ull) != 0ull);
                active &= ~supb;
                active &= ~(1ull << i);
            }
            if (lane == 0) km_s[c] = kmc;
        }
        if (lane == 0) cnt_s = cnt;
    }
    __syncthreads();
    int cnt = cnt_s;
    const u32* M = meta + b * K_PRE;
    const float* BX = box7 + (size_t)b * K_PRE * 7;
    const float* SS = tks + b * K_PRE;
    for (int p = tid; p < K_POST; p += 256) {
        float ob[7] = {0,0,0,0,0,0,0};
        float sc = 0.f, lb = 0.f, vd = 0.f;
        if (p < cnt) {
            int i = sel_s[p];
            float xg = BX[i*7+0], yg = BX[i*7+1], zg = BX[i*7+2];
            bool in_range = (xg >= 0.0f) && (xg <= 69.12f) &&
                            (yg >= -39.68f) && (yg <= 39.68f) &&
                            (zg >= -5.0f) && (zg <= 5.0f);
            if (in_range) {
                u32 mt = M[i];
                int dl = (mt >> 8) & 0xFF;
                float r = BX[i*7+6];
                bool opp = ((r > 0.0f) != (dl == 1));
                float rf = r + (opp ? 3.14159274f : 0.0f);
                ob[0]=xg; ob[1]=yg; ob[2]=zg; ob[3]=BX[i*7+3]; ob[4]=BX[i*7+4]; ob[5]=BX[i*7+5]; ob[6]=rf;
                sc = SS[i]; lb = (float)(mt & 0xFF); vd = 1.0f;
            }
        }
        size_t ro = (size_t)(b * K_POST + p);
        #pragma unroll
        for (int j = 0; j < 7; ++j) out[ro * 7 + j] = ob[j];
        out[(size_t)BB * K_POST * 7 + ro] = lb;
        out[(size_t)BB * K_POST * 8 + ro] = sc;
        out[(size_t)BB * K_POST * 9 + ro] = vd;
    }
}

extern "C" void kernel_launch(void* const* d_in, const int* in_sizes, int n_in,
                              void* d_out, int out_size, void* d_ws, size_t ws_size,
                              hipStream_t stream) {
    const float* boxp = (const float*)d_in[0];
    const float* cls  = (const float*)d_in[1];
    const float* dirp = (const float*)d_in[2];
    const float* anch = (const float*)d_in[3];
    float* out = (float*)d_out;
    char* ws = (char*)d_ws;

    void* args[] = { (void*)&boxp, (void*)&cls, (void*)&dirp, (void*)&anch, (void*)&out, (void*)&ws };
    hipError_t err = hipLaunchCooperativeKernel((const void*)k_mega, dim3(GRID), dim3(TPB),
                                                (void**)args, 0, stream);
    if (err != hipSuccess) {
        // Fallback: proven R12 7-kernel pipeline (identical math/semantics).
        char* p = ws;
        u32* key  = (u32*)p; p += (size_t)BB * NN * 4;
        u32* bh   = (u32*)p; p += (size_t)BB * SB * NBINS * 4;
        u32* part = (u32*)p; p += (size_t)BB * RED * NBINS * 4;
        u32* cnt  = (u32*)p; p += 256;
        u32* thr  = (u32*)p; p += 256;
        u32* boff = (u32*)p; p += (size_t)BB * SB * 4 + 256;
        u64* cand = (u64*)p; p += (size_t)BB * CAP * 8;
        float* tks = (float*)p; p += (size_t)BB * K_PRE * 4;
        u32* meta = (u32*)p; p += (size_t)BB * K_PRE * 4;
        float* box7 = (float*)p; p += (size_t)BB * K_PRE * 7 * 4;
        float* cor  = (float*)p; p += (size_t)BB * K_PRE * 5 * 4;
        u64* maskT = (u64*)p;

        k_score_hist<<<BB * SB, 256, 0, stream>>>(cls, key, bh);
        k_red<<<BB * RED * 9, 64, 0, stream>>>(bh, part);
        k_scanoff<<<BB, 512, 0, stream>>>(part, bh, thr, boff, cnt);
        k_scatter<<<BB * SB, 256, 0, stream>>>(key, thr, boff, cand);
        k_rankdec<<<BB * 16, 256, 0, stream>>>(cnt, cand, boxp, cls, dirp, anch, tks, meta, box7, cor);
        k_maskT<<<BB * 63, 256, 0, stream>>>(cor, maskT);
        k_nms_out<<<BB, 256, 0, stream>>>(meta, box7, tks, maskT, out);
    }
}

// Round 14
// 218.677 us; speedup vs baseline: 1.1883x; 1.1883x over previous
//
#include <hip/hip_runtime.h>
#include <hip/hip_cooperative_groups.h>
#include <stdint.h>

namespace cg = cooperative_groups;

typedef unsigned long long u64;
typedef unsigned int u32;

#define BB 4
#define NN 321408
#define K_PRE 1000
#define K_POST 300
#define CAP 4096
#define NW 16                 // 1000 bits -> 16 u64 words
#define SCORE_THR 0.05f
#define IOU_THR 0.5f
#define SB 314                // slice blocks per batch (ceil(NN/1024))
#define CH2 1024              // anchors per slice block
#define NBINS 576             // 16-bit key prefixes span 0xBD4C..0xBF80 (s in [0.05,1.0])
#define BIN0 0xBD4Cu
#define RED 8                 // wide 2-stage reduce (NEVER 4-block serial — R7/R11 lesson)
#define RCH 40
#define GRID 256              // cooperative tail grid: 1 block/CU (tail phases are narrow)
#define TPB 256

__device__ __forceinline__ float sigm(float x) { return 1.0f / (1.0f + expf(-x)); }

__device__ __forceinline__ u32 mkkey(float mx) {
    float s = sigm(mx);
    return (s >= SCORE_THR) ? (__float_as_uint(s) | 0x80000000u) : 0u;
}

// ---------------- K1 (WIDE standalone): keys + suffix-cumulative hist per slice ----------------
__global__ void k_score_hist(const float* __restrict__ cls, u32* __restrict__ key, u32* __restrict__ bh) {
    __shared__ u32 h1[NBINS], h2[NBINS];
    int bb = blockIdx.x, tid = threadIdx.x;       // grid = BB*SB
    int b = bb / SB, c = bb % SB;
    for (int i = tid; i < NBINS; i += 256) h1[i] = 0;
    __syncthreads();
    int a0 = c * CH2 + tid * 4;
    if (a0 < NN) {
        const float4* c4 = (const float4*)(cls + ((size_t)b * NN + a0) * 3);
        float4 v0 = c4[0], v1 = c4[1], v2 = c4[2];
        uint4 o;
        o.x = mkkey(fmaxf(v0.x, fmaxf(v0.y, v0.z)));
        o.y = mkkey(fmaxf(v0.w, fmaxf(v1.x, v1.y)));
        o.z = mkkey(fmaxf(v1.z, fmaxf(v1.w, v2.x)));
        o.w = mkkey(fmaxf(v2.y, fmaxf(v2.z, v2.w)));
        *((uint4*)(key + (size_t)b * NN + a0)) = o;
        if (o.x) atomicAdd(&h1[min((o.x >> 16) - BIN0, (u32)(NBINS - 1))], 1u);
        if (o.y) atomicAdd(&h1[min((o.y >> 16) - BIN0, (u32)(NBINS - 1))], 1u);
        if (o.z) atomicAdd(&h1[min((o.z >> 16) - BIN0, (u32)(NBINS - 1))], 1u);
        if (o.w) atomicAdd(&h1[min((o.w >> 16) - BIN0, (u32)(NBINS - 1))], 1u);
    }
    __syncthreads();
    u32* src = h1; u32* dst = h2;
    for (int off = 1; off < NBINS; off <<= 1) {
        for (int i = tid; i < NBINS; i += 256)
            dst[i] = src[i] + ((i + off < NBINS) ? src[i + off] : 0u);
        __syncthreads();
        u32* t = src; src = dst; dst = t;
    }
    for (int i = tid; i < NBINS; i += 256) bh[(size_t)bb * NBINS + i] = src[i];
}

// ---------------- shared-memory union for the cooperative tail ----------------
struct P3s { u32 tot[NBINS]; u32 wt[4]; u32 sT; u32 starg; };
struct P4s { u32 wtot[4]; };
struct P5s { u64 ck[CAP]; };
struct P6s { float s4[(K_PRE + 16) * 4]; float sA[K_PRE + 16]; };
struct P7s { u64 km[16]; int sel[K_POST]; int cnt_s; };
union SmemU { P3s p3; P4s p4; P5s p5; P6s p6; P7s p7; };

// ================= COOP TAIL: phases 2-7, 5 grid.sync()s replace 5 launch gaps =================
__global__ void __launch_bounds__(TPB) k_coop_tail(const float* __restrict__ boxp, const float* __restrict__ cls,
                                                   const float* __restrict__ dirp, const float* __restrict__ anch,
                                                   float* __restrict__ out, char* __restrict__ ws) {
    __shared__ SmemU sm;
    cg::grid_group gg = cg::this_grid();
    int bid = blockIdx.x, tid = threadIdx.x;
    int lane = tid & 63, wv = tid >> 6;

    char* p = ws;
    u32* key  = (u32*)p; p += (size_t)BB * NN * 4;
    u32* bh   = (u32*)p; p += (size_t)BB * SB * NBINS * 4;
    u32* part = (u32*)p; p += (size_t)BB * RED * NBINS * 4;
    u32* cnt  = (u32*)p; p += 256;
    u32* thr  = (u32*)p; p += 256;
    u32* boff = (u32*)p; p += (size_t)BB * SB * 4 + 256;
    u64* cand = (u64*)p; p += (size_t)BB * CAP * 8;
    float* tks = (float*)p; p += (size_t)BB * K_PRE * 4;
    u32* meta = (u32*)p; p += (size_t)BB * K_PRE * 4;
    float* box7 = (float*)p; p += (size_t)BB * K_PRE * 7 * 4;
    float* cor  = (float*)p; p += (size_t)BB * K_PRE * 5 * 4;
    u64* maskT = (u64*)p;

    // ---- Phase 2: wide column-sum of slice hists -> partials (96 blocks active) ----
    if (bid < BB * RED * 3) {
        int b = bid / (RED * 3), r = (bid / 3) % RED, g = bid % 3;
        int f = g * 256 + tid;
        if (f < NBINS) {
            int s0 = r * RCH, s1 = s0 + RCH; if (s1 > SB) s1 = SB;
            const u32* base = bh + (size_t)(b * SB + s0) * NBINS + f;
            u32 acc = 0; int n = s1 - s0;
            #pragma unroll 8
            for (int s = 0; s < n; ++s) acc += base[(size_t)s * NBINS];
            part[(size_t)(b * RED + r) * NBINS + f] = acc;
        }
    }
    gg.sync();

    // ---- Phase 3: threshold crossing + per-slice counts + prefix scan (4 blocks) ----
    if (bid < BB) {
        int b = bid;
        for (int f = tid; f < NBINS; f += TPB) {
            u32 x = 0;
            #pragma unroll
            for (int r = 0; r < RED; ++r) x += part[(size_t)(b * RED + r) * NBINS + f];
            sm.p3.tot[f] = x;
        }
        __syncthreads();
        if (tid == 0) {
            u32 tv = sm.p3.tot[0];
            sm.p3.starg = (tv < K_PRE) ? tv : K_PRE;
            if (sm.p3.starg == 0) { sm.p3.sT = 0x10000u; thr[b] = 0x10000u; }
        }
        __syncthreads();
        u32 target = sm.p3.starg;
        if (target > 0) {
            for (int f = tid; f < NBINS; f += TPB) {       // tot non-increasing -> unique crossing
                u32 cge = sm.p3.tot[f];
                u32 cnx = (f + 1 < NBINS) ? sm.p3.tot[f + 1] : 0u;
                if (cge >= target && cnx < target) { sm.p3.sT = BIN0 + (u32)f; thr[b] = BIN0 + (u32)f; }
            }
        }
        __syncthreads();
        u32 T = sm.p3.sT;
        u32 vA = 0, vB = 0;
        if (target > 0) {
            if (tid < SB) vA = bh[(size_t)(b * SB + tid) * NBINS + (T - BIN0)];
            if (tid + 256 < SB) vB = bh[(size_t)(b * SB + tid + 256) * NBINS + (T - BIN0)];
        }
        u32 x = vA;                                        // scan slices 0..255
        #pragma unroll
        for (int o = 1; o < 64; o <<= 1) { u32 y = __shfl_up(x, o); if (lane >= o) x += y; }
        if (lane == 63) sm.p3.wt[wv] = x;
        __syncthreads();
        u32 preA = 0, totA;
        { u32 w0 = sm.p3.wt[0], w1 = sm.p3.wt[1], w2 = sm.p3.wt[2], w3 = sm.p3.wt[3];
          if (wv > 0) preA += w0; if (wv > 1) preA += w1; if (wv > 2) preA += w2;
          totA = w0 + w1 + w2 + w3; }
        __syncthreads();
        u32 xb = vB;                                       // scan slices 256..313
        #pragma unroll
        for (int o = 1; o < 64; o <<= 1) { u32 y = __shfl_up(xb, o); if (lane >= o) xb += y; }
        if (lane == 63) sm.p3.wt[wv] = xb;
        __syncthreads();
        u32 preB = 0, totB;
        { u32 w0 = sm.p3.wt[0], w1 = sm.p3.wt[1], w2 = sm.p3.wt[2], w3 = sm.p3.wt[3];
          if (wv > 0) preB += w0; if (wv > 1) preB += w1; if (wv > 2) preB += w2;
          totB = w0 + w1 + w2 + w3; }
        if (tid < SB) boff[b * SB + tid] = preA + x - vA;
        if (tid + 256 < SB) boff[b * SB + tid + 256] = totA + preB + xb - vB;
        if (tid == 0) cnt[b] = totA + totB;
    }
    gg.sync();

    // ---- Phase 4: scatter candidates at prefix offsets (grid-stride 1256 tasks) ----
    for (int task = bid; task < BB * SB; task += GRID) {
        int b = task / SB, c = task % SB;
        u32 T = thr[b];
        int a0 = c * CH2 + tid * 4;
        uint4 kk = make_uint4(0u, 0u, 0u, 0u);
        if (a0 < NN) kk = *((const uint4*)(key + (size_t)b * NN + a0));
        u32 ks[4] = {kk.x, kk.y, kk.z, kk.w};
        u32 f[4];
        #pragma unroll
        for (int e = 0; e < 4; ++e) f[e] = (u32)((ks[e] != 0) && ((ks[e] >> 16) >= T));
        u32 tc = f[0] + f[1] + f[2] + f[3];
        u32 x = tc;
        #pragma unroll
        for (int o = 1; o < 64; o <<= 1) { u32 y = __shfl_up(x, o); if (lane >= o) x += y; }
        if (lane == 63) sm.p4.wtot[wv] = x;
        __syncthreads();
        u32 base = 0;
        { u32 w0 = sm.p4.wtot[0], w1 = sm.p4.wtot[1], w2 = sm.p4.wtot[2];
          if (wv > 0) base += w0; if (wv > 1) base += w1; if (wv > 2) base += w2; }
        u32 pos = boff[task] + base + x - tc;
        u64* cb = cand + (size_t)b * CAP;
        #pragma unroll
        for (int e = 0; e < 4; ++e) {
            if (f[e]) {                                    // candidate SET; order irrelevant
                if (pos < CAP) cb[pos] = ((u64)(~ks[e]) << 32) | (u64)(a0 + e);
                ++pos;
            }
        }
        __syncthreads();
    }
    gg.sync();

    // ---- Phase 5: rank (64 cand/block, 1-wave LDS-broadcast scan) + decode ----
    {
        int b = bid >> 6, g = bid & 63;                    // 256 blocks exactly
        u32 nc = cnt[b]; if (nc > CAP) nc = CAP;
        int ci0 = g * 64;
        bool active = (ci0 < (int)nc) || (ci0 < K_PRE);    // block-uniform
        if (active) {
            const u64* cb = cand + (size_t)b * CAP;
            for (int i = tid; i < (int)nc; i += TPB) sm.p5.ck[i] = cb[i];
            __syncthreads();
            int rank = -1; u32 idx = 0xFFFFFFFFu;
            if (tid < 64) {
                int ci = ci0 + tid;
                if (ci < (int)nc) {
                    u64 my = sm.p5.ck[ci];
                    u32 r = 0;
                    int j = 0, nlim = (int)nc & ~15;
                    for (; j < nlim; j += 16) {            // 16 uniform broadcast reads in flight
                        u64 v0 = sm.p5.ck[j+0], v1 = sm.p5.ck[j+1], v2 = sm.p5.ck[j+2], v3 = sm.p5.ck[j+3];
                        u64 v4 = sm.p5.ck[j+4], v5 = sm.p5.ck[j+5], v6 = sm.p5.ck[j+6], v7 = sm.p5.ck[j+7];
                        u64 v8 = sm.p5.ck[j+8], v9 = sm.p5.ck[j+9], va = sm.p5.ck[j+10], vb = sm.p5.ck[j+11];
                        u64 vc = sm.p5.ck[j+12], vd = sm.p5.ck[j+13], ve = sm.p5.ck[j+14], vf = sm.p5.ck[j+15];
                        r += (u32)(v0 < my) + (u32)(v1 < my) + (u32)(v2 < my) + (u32)(v3 < my)
                           + (u32)(v4 < my) + (u32)(v5 < my) + (u32)(v6 < my) + (u32)(v7 < my)
                           + (u32)(v8 < my) + (u32)(v9 < my) + (u32)(va < my) + (u32)(vb < my)
                           + (u32)(vc < my) + (u32)(vd < my) + (u32)(ve < my) + (u32)(vf < my);
                    }
                    for (; j < (int)nc; ++j) r += (u32)(sm.p5.ck[j] < my);
                    if (r < K_PRE) { rank = (int)r; idx = (u32)my; }
                } else if (ci < K_PRE) {
                    rank = ci;                             // filler (disjoint from real ranks)
                }
            }
            if (rank >= 0) {
                float ob[7] = {0,0,0,0,0,0,0};
                float c5[5] = {0,0,0,0,0};
                float sc = 0.f; u32 mt = 0;
                if (idx != 0xFFFFFFFFu) {
                    const float* A = anch + (size_t)idx * 7;
                    const float* D = boxp + ((size_t)b * NN + idx) * 7;
                    float xa=A[0], ya=A[1], za=A[2], wa=A[3], la=A[4], ha=A[5], ra=A[6];
                    float xt=D[0], yt=D[1], zt=D[2], wt2=D[3], lt=D[4], ht=D[5], rt=D[6];
                    za = za + ha * 0.5f;
                    float diag = sqrtf(la * la + wa * wa);
                    float xg = xt * diag + xa;
                    float yg = yt * diag + ya;
                    float zg = zt * ha + za;
                    float wg = expf(wt2) * wa;
                    float lg = expf(lt) * la;
                    float hg = expf(ht) * ha;
                    zg = zg - hg * 0.5f;
                    float rg = rt + ra;
                    ob[0]=xg; ob[1]=yg; ob[2]=zg; ob[3]=wg; ob[4]=lg; ob[5]=hg; ob[6]=rg;
                    float cr = fabsf(cosf(rg)), sr = fabsf(sinf(rg));
                    float hx = 0.5f * (wg * cr + lg * sr);
                    float hy = 0.5f * (wg * sr + lg * cr);
                    float x1 = xg - hx, x2 = xg + hx, y1 = yg - hy, y2 = yg + hy;
                    c5[0]=x1; c5[1]=x2; c5[2]=y1; c5[3]=y2; c5[4]=(x2-x1)*(y2-y1);
                    const float* cc = cls + ((size_t)b * NN + idx) * 3;
                    float p0 = sigm(cc[0]), p1 = sigm(cc[1]), p2 = sigm(cc[2]);
                    int lbl = 0; float best = p0;
                    if (p1 > best) { best = p1; lbl = 1; }
                    if (p2 > best) { best = p2; lbl = 2; }
                    sc = best;
                    const float* dd = dirp + ((size_t)b * NN + idx) * 2;
                    int dl = (dd[1] > dd[0]) ? 1 : 0;
                    mt = (u32)lbl | ((u32)dl << 8) | (1u << 16);
                }
                size_t t = (size_t)b * K_PRE + rank;
                tks[t] = sc; meta[t] = mt;
                #pragma unroll
                for (int j = 0; j < 7; ++j) box7[t * 7 + j] = ob[j];
                #pragma unroll
                for (int j = 0; j < 5; ++j) cor[t * 5 + j] = c5[j];
            }
        }
    }
    gg.sync();

    // ---- Phase 6: transposed suppression bitmask (252 blocks active) ----
    if (bid < BB * 63) {
        int b = bid / 63, jb = bid % 63;
        const float4* C4 = (const float4*)(cor + (size_t)b * K_PRE * 5);
        for (int q = tid; q < (K_PRE * 5) / 4; q += TPB) {
            float4 v = C4[q];
            int t0 = q * 4;
            #pragma unroll
            for (int e = 0; e < 4; ++e) {
                int t = t0 + e;
                int i = t / 5, k = t - i * 5;
                float val = (e == 0) ? v.x : (e == 1) ? v.y : (e == 2) ? v.z : v.w;
                int ip = i + (i >> 6);
                if (k < 4) sm.p6.s4[ip * 4 + k] = val; else sm.p6.sA[ip] = val;
            }
        }
        __syncthreads();
        int w = tid & 15, jl = tid >> 4;
        int j = jb * 16 + jl;
        if (j < K_PRE) {
            int jp = j + (j >> 6);
            float x1 = sm.p6.s4[jp*4+0], x2 = sm.p6.s4[jp*4+1];
            float y1 = sm.p6.s4[jp*4+2], y2 = sm.p6.s4[jp*4+3], ar = sm.p6.sA[jp];
            u64 m = 0;
            int i0 = w * 64;
            if (i0 < j) {
                int iend = j - i0; if (iend > 64) iend = 64;
                for (int ii = 0; ii < iend; ++ii) {
                    int i = i0 + ii;
                    int ip = i + (i >> 6);
                    float4 bx = *(const float4*)&sm.p6.s4[ip * 4];
                    float ai = sm.p6.sA[ip];
                    float ix = fminf(x2, bx.y) - fmaxf(x1, bx.x); ix = fmaxf(ix, 0.f);
                    float iy = fminf(y2, bx.w) - fmaxf(y1, bx.z); iy = fmaxf(iy, 0.f);
                    float inter = ix * iy;
                    float uni = ai + ar - inter;
                    float iou = (uni > 0.f) ? inter / fmaxf(uni, 1e-12f) : 0.f;
                    if (iou > IOU_THR) m |= (1ull << ii);
                }
            }
            maskT[((size_t)b * K_PRE + j) * NW + w] = m;
        }
    }
    gg.sync();

    // ---- Phase 7: greedy NMS over kept boxes + outputs (4 blocks) ----
    if (bid < BB) {
        int b = bid;
        if (tid < 16) sm.p7.km[tid] = 0ull;
        __syncthreads();
        if (tid < 64) {
            int c2 = 0; bool done = false;
            const u32* M = meta + b * K_PRE;
            for (int c = 0; c < 16; ++c) {
                if (done) break;
                int j = c * 64 + lane;
                int jc = (j < K_PRE) ? j : (K_PRE - 1);
                bool jvalid = (j < K_PRE) && ((M[jc] >> 16) & 1u);
                const u64* colp = maskT + ((size_t)b * K_PRE + jc) * NW;
                u64 cw = 0; u64 supacc = 0;
                #pragma unroll
                for (int w = 0; w < 16; ++w) {
                    u64 cv = colp[w];
                    supacc |= (cv & sm.p7.km[w]);
                    if (w == c) cw = cv;
                }
                u64 active2 = __ballot(jvalid && (supacc == 0ull));
                u64 kmc = 0;
                while (active2) {
                    int i = __ffsll((unsigned long long)active2) - 1;
                    if (lane == 0) sm.p7.sel[c2] = c * 64 + i;
                    ++c2;
                    if (c2 >= K_POST) { done = true; break; }
                    kmc |= (1ull << i);
                    u64 supb = __ballot(((cw >> i) & 1ull) != 0ull);
                    active2 &= ~supb;
                    active2 &= ~(1ull << i);
                }
                if (lane == 0) sm.p7.km[c] = kmc;
            }
            if (lane == 0) sm.p7.cnt_s = c2;
        }
        __syncthreads();
        int kept = sm.p7.cnt_s;
        const u32* M = meta + b * K_PRE;
        const float* BX = box7 + (size_t)b * K_PRE * 7;
        const float* SS = tks + b * K_PRE;
        for (int pp = tid; pp < K_POST; pp += TPB) {
            float ob[7] = {0,0,0,0,0,0,0};
            float sc = 0.f, lb = 0.f, vd = 0.f;
            if (pp < kept) {
                int i = sm.p7.sel[pp];
                float xg = BX[i*7+0], yg = BX[i*7+1], zg = BX[i*7+2];
                bool in_range = (xg >= 0.0f) && (xg <= 69.12f) &&
                                (yg >= -39.68f) && (yg <= 39.68f) &&
                                (zg >= -5.0f) && (zg <= 5.0f);
                if (in_range) {
                    u32 mt = M[i];
                    int dl = (mt >> 8) & 0xFF;
                    float r = BX[i*7+6];
                    bool opp = ((r > 0.0f) != (dl == 1));
                    float rf = r + (opp ? 3.14159274f : 0.0f);
                    ob[0]=xg; ob[1]=yg; ob[2]=zg; ob[3]=BX[i*7+3]; ob[4]=BX[i*7+4]; ob[5]=BX[i*7+5]; ob[6]=rf;
                    sc = SS[i]; lb = (float)(mt & 0xFF); vd = 1.0f;
                }
            }
            size_t ro = (size_t)(b * K_POST + pp);
            #pragma unroll
            for (int j = 0; j < 7; ++j) out[ro * 7 + j] = ob[j];
            out[(size_t)BB * K_POST * 7 + ro] = lb;
            out[(size_t)BB * K_POST * 8 + ro] = sc;
            out[(size_t)BB * K_POST * 9 + ro] = vd;
        }
    }
}

// ================= FALLBACK: proven R12 kernels 2-7 =================
__global__ __launch_bounds__(64) void k_red(const u32* __restrict__ bh, u32* __restrict__ part) {
    int blk = blockIdx.x, tid = threadIdx.x;
    int b = blk / (RED * 9); int r = (blk / 9) % RED; int g = blk % 9;
    int f = g * 64 + tid;
    int s0 = r * RCH, s1 = s0 + RCH; if (s1 > SB) s1 = SB;
    const u32* base = bh + (size_t)(b * SB + s0) * NBINS + f;
    u32 acc = 0; int n = s1 - s0;
    #pragma unroll 8
    for (int s = 0; s < n; ++s) acc += base[(size_t)s * NBINS];
    part[(size_t)(b * RED + r) * NBINS + f] = acc;
}

__global__ __launch_bounds__(512) void k_scanoff(const u32* __restrict__ part, const u32* __restrict__ bh,
                                                 u32* __restrict__ thr, u32* __restrict__ boff,
                                                 u32* __restrict__ cnt) {
    __shared__ u32 tot[NBINS];
    __shared__ u32 wt[8];
    __shared__ u32 sT, starg;
    int b = blockIdx.x, tid = threadIdx.x;
    for (int f = tid; f < NBINS; f += 512) {
        u32 x = 0;
        #pragma unroll
        for (int r = 0; r < RED; ++r) x += part[(size_t)(b * RED + r) * NBINS + f];
        tot[f] = x;
    }
    __syncthreads();
    if (tid == 0) {
        u32 tv = tot[0];
        starg = (tv < K_PRE) ? tv : K_PRE;
        if (starg == 0) { sT = 0x10000u; thr[b] = 0x10000u; }
    }
    __syncthreads();
    u32 target = starg;
    if (target > 0) {
        for (int f = tid; f < NBINS; f += 512) {
            u32 cge = tot[f];
            u32 cnx = (f + 1 < NBINS) ? tot[f + 1] : 0u;
            if (cge >= target && cnx < target) { sT = BIN0 + (u32)f; thr[b] = BIN0 + (u32)f; }
        }
    }
    __syncthreads();
    u32 v = 0;
    if (target > 0 && tid < SB) v = bh[(size_t)(b * SB + tid) * NBINS + (sT - BIN0)];
    int lane = tid & 63, wv = tid >> 6;
    u32 x = v;
    #pragma unroll
    for (int o = 1; o < 64; o <<= 1) { u32 y = __shfl_up(x, o); if (lane >= o) x += y; }
    if (lane == 63) wt[wv] = x;
    __syncthreads();
    u32 pre = 0;
    #pragma unroll
    for (int w = 0; w < 7; ++w) pre += (w < wv) ? wt[w] : 0u;
    if (tid < SB) boff[b * SB + tid] = pre + x - v;
    if (tid == 511) cnt[b] = pre + x;
}

__global__ void k_scatter(const u32* __restrict__ key, const u32* __restrict__ thr,
                          const u32* __restrict__ boff, u64* __restrict__ cand) {
    __shared__ u32 wtot[4];
    int bb = blockIdx.x, tid = threadIdx.x;
    int b = bb / SB, c = bb % SB;
    u32 T = thr[b];
    int a0 = c * CH2 + tid * 4;
    uint4 kk = make_uint4(0u, 0u, 0u, 0u);
    if (a0 < NN) kk = *((const uint4*)(key + (size_t)b * NN + a0));
    u32 ks[4] = {kk.x, kk.y, kk.z, kk.w};
    u32 f[4];
    #pragma unroll
    for (int e = 0; e < 4; ++e) f[e] = (u32)((ks[e] != 0) && ((ks[e] >> 16) >= T));
    u32 tc = f[0] + f[1] + f[2] + f[3];
    int lane = tid & 63, wv = tid >> 6;
    u32 x = tc;
    #pragma unroll
    for (int o = 1; o < 64; o <<= 1) { u32 y = __shfl_up(x, o); if (lane >= o) x += y; }
    if (lane == 63) wtot[wv] = x;
    __syncthreads();
    u32 base = 0;
    u32 w0 = wtot[0], w1 = wtot[1], w2 = wtot[2];
    if (wv > 0) base += w0;
    if (wv > 1) base += w1;
    if (wv > 2) base += w2;
    u32 pos = boff[bb] + base + x - tc;
    u64* cb = cand + (size_t)b * CAP;
    #pragma unroll
    for (int e = 0; e < 4; ++e) {
        if (f[e]) {
            if (pos < CAP) cb[pos] = ((u64)(~ks[e]) << 32) | (u64)(a0 + e);
            ++pos;
        }
    }
}

__global__ __launch_bounds__(256) void k_rankdec(const u32* __restrict__ cnt, const u64* __restrict__ cand,
                                                 const float* __restrict__ boxp, const float* __restrict__ cls,
                                                 const float* __restrict__ dirp, const float* __restrict__ anch,
                                                 float* __restrict__ tks, u32* __restrict__ meta,
                                                 float* __restrict__ box7, float* __restrict__ cor) {
    __shared__ u64 ck[CAP];
    int blk = blockIdx.x, tid = threadIdx.x;
    int b = blk >> 4, rb = blk & 15;
    u32 nc = cnt[b]; if (nc > CAP) nc = CAP;
    int ci = rb * 256 + tid;
    if (rb * 256 >= (int)nc && rb * 256 >= K_PRE) return;
    const u64* cb = cand + (size_t)b * CAP;
    for (int i = tid; i < (int)nc; i += 256) ck[i] = cb[i];
    __syncthreads();
    int rank = -1; u32 idx = 0xFFFFFFFFu;
    if (ci < (int)nc) {
        u64 my = ck[ci];
        u32 r = 0;
        int j = 0, nlim = (int)nc & ~15;
        for (; j < nlim; j += 16) {
            u64 v0 = ck[j+0], v1 = ck[j+1], v2 = ck[j+2], v3 = ck[j+3];
            u64 v4 = ck[j+4], v5 = ck[j+5], v6 = ck[j+6], v7 = ck[j+7];
            u64 v8 = ck[j+8], v9 = ck[j+9], va = ck[j+10], vb = ck[j+11];
            u64 vc = ck[j+12], vd = ck[j+13], ve = ck[j+14], vf = ck[j+15];
            r += (u32)(v0 < my) + (u32)(v1 < my) + (u32)(v2 < my) + (u32)(v3 < my)
               + (u32)(v4 < my) + (u32)(v5 < my) + (u32)(v6 < my) + (u32)(v7 < my)
               + (u32)(v8 < my) + (u32)(v9 < my) + (u32)(va < my) + (u32)(vb < my)
               + (u32)(vc < my) + (u32)(vd < my) + (u32)(ve < my) + (u32)(vf < my);
        }
        for (; j < (int)nc; ++j) r += (u32)(ck[j] < my);
        if (r < K_PRE) { rank = (int)r; idx = (u32)my; }
    } else if (ci < K_PRE) {
        rank = ci;
    }
    if (rank < 0) return;
    float ob[7] = {0,0,0,0,0,0,0};
    float c5[5] = {0,0,0,0,0};
    float sc = 0.f; u32 mt = 0;
    if (idx != 0xFFFFFFFFu) {
        const float* A = anch + (size_t)idx * 7;
        const float* D = boxp + ((size_t)b * NN + idx) * 7;
        float xa=A[0], ya=A[1], za=A[2], wa=A[3], la=A[4], ha=A[5], ra=A[6];
        float xt=D[0], yt=D[1], zt=D[2], wt=D[3], lt=D[4], ht=D[5], rt=D[6];
        za = za + ha * 0.5f;
        float diag = sqrtf(la * la + wa * wa);
        float xg = xt * diag + xa;
        float yg = yt * diag + ya;
        float zg = zt * ha + za;
        float wg = expf(wt) * wa;
        float lg = expf(lt) * la;
        float hg = expf(ht) * ha;
        zg = zg - hg * 0.5f;
        float rg = rt + ra;
        ob[0]=xg; ob[1]=yg; ob[2]=zg; ob[3]=wg; ob[4]=lg; ob[5]=hg; ob[6]=rg;
        float cr = fabsf(cosf(rg)), sr = fabsf(sinf(rg));
        float hx = 0.5f * (wg * cr + lg * sr);
        float hy = 0.5f * (wg * sr + lg * cr);
        float x1 = xg - hx, x2 = xg + hx, y1 = yg - hy, y2 = yg + hy;
        c5[0]=x1; c5[1]=x2; c5[2]=y1; c5[3]=y2; c5[4]=(x2-x1)*(y2-y1);
        const float* cc = cls + ((size_t)b * NN + idx) * 3;
        float p0 = sigm(cc[0]), p1 = sigm(cc[1]), p2 = sigm(cc[2]);
        int lbl = 0; float best = p0;
        if (p1 > best) { best = p1; lbl = 1; }
        if (p2 > best) { best = p2; lbl = 2; }
        sc = best;
        const float* dd = dirp + ((size_t)b * NN + idx) * 2;
        int dl = (dd[1] > dd[0]) ? 1 : 0;
        mt = (u32)lbl | ((u32)dl << 8) | (1u << 16);
    }
    size_t t = (size_t)b * K_PRE + rank;
    tks[t] = sc; meta[t] = mt;
    #pragma unroll
    for (int j = 0; j < 7; ++j) box7[t * 7 + j] = ob[j];
    #pragma unroll
    for (int j = 0; j < 5; ++j) cor[t * 5 + j] = c5[j];
}

__global__ __launch_bounds__(256) void k_maskT(const float* __restrict__ cor, u64* __restrict__ maskT) {
    __shared__ float s4[(K_PRE + 16) * 4];
    __shared__ float sA[K_PRE + 16];
    int blk = blockIdx.x;
    int b = blk / 63, jb = blk % 63;
    int tid = threadIdx.x;
    const float4* C4 = (const float4*)(cor + (size_t)b * K_PRE * 5);
    for (int q = tid; q < (K_PRE * 5) / 4; q += 256) {
        float4 v = C4[q];
        int t0 = q * 4;
        #pragma unroll
        for (int e = 0; e < 4; ++e) {
            int t = t0 + e;
            int i = t / 5, k = t - i * 5;
            float val = (e == 0) ? v.x : (e == 1) ? v.y : (e == 2) ? v.z : v.w;
            int ip = i + (i >> 6);
            if (k < 4) s4[ip * 4 + k] = val; else sA[ip] = val;
        }
    }
    __syncthreads();
    int w = tid & 15, jl = tid >> 4;
    int j = jb * 16 + jl;
    if (j >= K_PRE) return;
    int jp = j + (j >> 6);
    float x1 = s4[jp*4+0], x2 = s4[jp*4+1], y1 = s4[jp*4+2], y2 = s4[jp*4+3], ar = sA[jp];
    u64 m = 0;
    int i0 = w * 64;
    if (i0 < j) {
        int iend = j - i0; if (iend > 64) iend = 64;
        for (int ii = 0; ii < iend; ++ii) {
            int i = i0 + ii;
            int ip = i + (i >> 6);
            float4 bx = *(const float4*)&s4[ip * 4];
            float ai = sA[ip];
            float ix = fminf(x2, bx.y) - fmaxf(x1, bx.x); ix = fmaxf(ix, 0.f);
            float iy = fminf(y2, bx.w) - fmaxf(y1, bx.z); iy = fmaxf(iy, 0.f);
            float inter = ix * iy;
            float uni = ai + ar - inter;
            float iou = (uni > 0.f) ? inter / fmaxf(uni, 1e-12f) : 0.f;
            if (iou > IOU_THR) m |= (1ull << ii);
        }
    }
    maskT[((size_t)b * K_PRE + j) * NW + w] = m;
}

__global__ __launch_bounds__(256) void k_nms_out(const u32* __restrict__ meta, const float* __restrict__ box7,
                                                 const float* __restrict__ tks, const u64* __restrict__ maskT,
                                                 float* __restrict__ out) {
    int b = blockIdx.x; int tid = threadIdx.x;
    __shared__ u64 km_s[16];
    __shared__ int sel_s[K_POST];
    __shared__ int cnt_s;
    if (tid < 16) km_s[tid] = 0ull;
    __syncthreads();
    if (tid < 64) {
        int lane = tid;
        const u32* M = meta + b * K_PRE;
        int cnt = 0; bool done = false;
        for (int c = 0; c < 16; ++c) {
            if (done) break;
            int j = c * 64 + lane;
            int jc = (j < K_PRE) ? j : (K_PRE - 1);
            bool jvalid = (j < K_PRE) && ((M[jc] >> 16) & 1u);
            const u64* colp = maskT + ((size_t)b * K_PRE + jc) * NW;
            u64 cw = 0; u64 supacc = 0;
            #pragma unroll
            for (int w = 0; w < 16; ++w) {
                u64 cv = colp[w];
                supacc |= (cv & km_s[w]);
                if (w == c) cw = cv;
            }
            u64 active = __ballot(jvalid && (supacc == 0ull));
            u64 kmc = 0;
            while (active) {
                int i = __ffsll((unsigned long long)active) - 1;
                if (lane == 0) sel_s[cnt] = c * 64 + i;
                ++cnt;
                if (cnt >= K_POST) { done = true; break; }
                kmc |= (1ull << i);
                u64 supb = __ballot(((cw >> i) & 1ull) != 0ull);
                active &= ~supb;
                active &= ~(1ull << i);
            }
            if (lane == 0) km_s[c] = kmc;
        }
        if (lane == 0) cnt_s = cnt;
    }
    __syncthreads();
    int cnt = cnt_s;
    const u32* M = meta + b * K_PRE;
    const float* BX = box7 + (size_t)b * K_PRE * 7;
    const float* SS = tks + b * K_PRE;
    for (int p = tid; p < K_POST; p += 256) {
        float ob[7] = {0,0,0,0,0,0,0};
        float sc = 0.f, lb = 0.f, vd = 0.f;
        if (p < cnt) {
            int i = sel_s[p];
            float xg = BX[i*7+0], yg = BX[i*7+1], zg = BX[i*7+2];
            bool in_range = (xg >= 0.0f) && (xg <= 69.12f) &&
                            (yg >= -39.68f) && (yg <= 39.68f) &&
                            (zg >= -5.0f) && (zg <= 5.0f);
            if (in_range) {
                u32 mt = M[i];
                int dl = (mt >> 8) & 0xFF;
                float r = BX[i*7+6];
                bool opp = ((r > 0.0f) != (dl == 1));
                float rf = r + (opp ? 3.14159274f : 0.0f);
                ob[0]=xg; ob[1]=yg; ob[2]=zg; ob[3]=BX[i*7+3]; ob[4]=BX[i*7+4]; ob[5]=BX[i*7+5]; ob[6]=rf;
                sc = SS[i]; lb = (float)(mt & 0xFF); vd = 1.0f;
            }
        }
        size_t ro = (size_t)(b * K_POST + p);
        #pragma unroll
        for (int j = 0; j < 7; ++j) out[ro * 7 + j] = ob[j];
        out[(size_t)BB * K_POST * 7 + ro] = lb;
        out[(size_t)BB * K_POST * 8 + ro] = sc;
        out[(size_t)BB * K_POST * 9 + ro] = vd;
    }
}

extern "C" void kernel_launch(void* const* d_in, const int* in_sizes, int n_in,
                              void* d_out, int out_size, void* d_ws, size_t ws_size,
                              hipStream_t stream) {
    const float* boxp = (const float*)d_in[0];
    const float* cls  = (const float*)d_in[1];
    const float* dirp = (const float*)d_in[2];
    const float* anch = (const float*)d_in[3];
    float* out = (float*)d_out;
    char* ws = (char*)d_ws;

    char* p = ws;
    u32* key  = (u32*)p; p += (size_t)BB * NN * 4;
    u32* bh   = (u32*)p; p += (size_t)BB * SB * NBINS * 4;

    // Phase 1: wide standalone (needs full occupancy — R13 lesson)
    k_score_hist<<<BB * SB, 256, 0, stream>>>(cls, key, bh);

    // Phases 2-7: cooperative tail (narrow phases; 5 grid.syncs replace 5 launch gaps)
    void* args[] = { (void*)&boxp, (void*)&cls, (void*)&dirp, (void*)&anch, (void*)&out, (void*)&ws };
    hipError_t err = hipLaunchCooperativeKernel((const void*)k_coop_tail, dim3(GRID), dim3(TPB),
                                                (void**)args, 0, stream);
    if (err != hipSuccess) {
        // Fallback: proven R12 kernels 2-7 (identical math/semantics).
        u32* part = (u32*)p; p += (size_t)BB * RED * NBINS * 4;
        u32* cnt  = (u32*)p; p += 256;
        u32* thr  = (u32*)p; p += 256;
        u32* boff = (u32*)p; p += (size_t)BB * SB * 4 + 256;
        u64* cand = (u64*)p; p += (size_t)BB * CAP * 8;
        float* tks = (float*)p; p += (size_t)BB * K_PRE * 4;
        u32* meta = (u32*)p; p += (size_t)BB * K_PRE * 4;
        float* box7 = (float*)p; p += (size_t)BB * K_PRE * 7 * 4;
        float* cor  = (float*)p; p += (size_t)BB * K_PRE * 5 * 4;
        u64* maskT = (u64*)p;

        k_red<<<BB * RED * 9, 64, 0, stream>>>(bh, part);
        k_scanoff<<<BB, 512, 0, stream>>>(part, bh, thr, boff, cnt);
        k_scatter<<<BB * SB, 256, 0, stream>>>(key, thr, boff, cand);
        k_rankdec<<<BB * 16, 256, 0, stream>>>(cnt, cand, boxp, cls, dirp, anch, tks, meta, box7, cor);
        k_maskT<<<BB * 63, 256, 0, stream>>>(cor, maskT);
        k_nms_out<<<BB, 256, 0, stream>>>(meta, box7, tks, maskT, out);
    }
}

// Round 15
// 87.155 us; speedup vs baseline: 2.9814x; 2.5091x over previous
//
#include <hip/hip_runtime.h>
#include <stdint.h>

typedef unsigned long long u64;
typedef unsigned int u32;

#define BB 4
#define NN 321408
#define K_PRE 1000
#define K_POST 300
#define CAP 4096
#define NW 16                 // 1000 bits -> 16 u64 words
#define SCORE_THR 0.05f
#define IOU_THR 0.5f
#define SB 314                // slice blocks per batch (ceil(NN/1024))
#define CH2 1024              // anchors per slice block
#define NBINS 576             // 16-bit key prefixes span 0xBD4C..0xBF80 (s in [0.05,1.0])
#define BIN0 0xBD4Cu
#define RED 8                 // wide 2-stage reduce (NEVER 4-block serial — R7/R11 lesson)
#define RCH 40

__device__ __forceinline__ float sigm(float x) { return 1.0f / (1.0f + expf(-x)); }

__device__ __forceinline__ u32 mkkey(float mx) {
    float s = sigm(mx);
    return (s >= SCORE_THR) ? (__float_as_uint(s) | 0x80000000u) : 0u;
}

// ---------------- K1: keys + 576-bin LDS hist, stored SUFFIX-cumulative per slice ----------------
// bh[slice][f] = #keys in slice with bin >= f  (bin = (key>>16) - BIN0)
__global__ void k_score_hist(const float* __restrict__ cls, u32* __restrict__ key, u32* __restrict__ bh) {
    __shared__ u32 h1[NBINS], h2[NBINS];
    int bb = blockIdx.x, tid = threadIdx.x;       // grid = BB*SB
    int b = bb / SB, c = bb % SB;
    for (int i = tid; i < NBINS; i += 256) h1[i] = 0;
    __syncthreads();
    int a0 = c * CH2 + tid * 4;                   // NN % 4 == 0: full quads only
    if (a0 < NN) {
        const float4* c4 = (const float4*)(cls + ((size_t)b * NN + a0) * 3);
        float4 v0 = c4[0], v1 = c4[1], v2 = c4[2];
        uint4 o;
        o.x = mkkey(fmaxf(v0.x, fmaxf(v0.y, v0.z)));
        o.y = mkkey(fmaxf(v0.w, fmaxf(v1.x, v1.y)));
        o.z = mkkey(fmaxf(v1.z, fmaxf(v1.w, v2.x)));
        o.w = mkkey(fmaxf(v2.y, fmaxf(v2.z, v2.w)));
        *((uint4*)(key + (size_t)b * NN + a0)) = o;
        if (o.x) atomicAdd(&h1[min((o.x >> 16) - BIN0, (u32)(NBINS - 1))], 1u);
        if (o.y) atomicAdd(&h1[min((o.y >> 16) - BIN0, (u32)(NBINS - 1))], 1u);
        if (o.z) atomicAdd(&h1[min((o.z >> 16) - BIN0, (u32)(NBINS - 1))], 1u);
        if (o.w) atomicAdd(&h1[min((o.w >> 16) - BIN0, (u32)(NBINS - 1))], 1u);
    }
    __syncthreads();
    // suffix scan (Hillis-Steele, double-buffered): src[i] = sum_{j>=i} hist[j]
    u32* src = h1; u32* dst = h2;
    for (int off = 1; off < NBINS; off <<= 1) {   // 10 passes
        for (int i = tid; i < NBINS; i += 256)
            dst[i] = src[i] + ((i + off < NBINS) ? src[i + off] : 0u);
        __syncthreads();
        u32* t = src; src = dst; dst = t;
    }
    for (int i = tid; i < NBINS; i += 256) bh[(size_t)bb * NBINS + i] = src[i];
}

// ---------------- K2: WIDE column-sum of slice suffix-hists -> partials ----------------
__global__ __launch_bounds__(64) void k_red(const u32* __restrict__ bh, u32* __restrict__ part) {
    int blk = blockIdx.x, tid = threadIdx.x;      // grid = BB*RED*9, block = 64
    int b = blk / (RED * 9);
    int r = (blk / 9) % RED;
    int g = blk % 9;
    int f = g * 64 + tid;                          // < 576
    int s0 = r * RCH, s1 = s0 + RCH; if (s1 > SB) s1 = SB;
    const u32* base = bh + (size_t)(b * SB + s0) * NBINS + f;
    u32 acc = 0;
    int n = s1 - s0;
    #pragma unroll 8
    for (int s = 0; s < n; ++s) acc += base[(size_t)s * NBINS];
    part[(size_t)(b * RED + r) * NBINS + f] = acc;
}

// ---------------- K3 (fused scanoff+scatter): per-block threshold + own offset + scatter ----------------
// Each block derives: tot[] (sum of 8 partials, L2-broadcast), threshold Tf (unique crossing of
// non-increasing suffix array), its own base offset (sum of bh[s][Tf] for s < c), then scatters.
// Candidate ORDER is irrelevant (rank phase sorts by key); only the SET + unique slots matter.
__global__ __launch_bounds__(256) void k_scatterT(const u32* __restrict__ key, const u32* __restrict__ part,
                                                  const u32* __restrict__ bh, u32* __restrict__ cnt,
                                                  u64* __restrict__ cand) {
    __shared__ u32 tot[NBINS];
    __shared__ u32 wtot[4];
    __shared__ u32 sTf;
    int bb = blockIdx.x, tid = threadIdx.x;       // grid = BB*SB
    int b = bb / SB, c = bb % SB;
    int lane = tid & 63, wv = tid >> 6;
    for (int f = tid; f < NBINS; f += 256) {
        u32 x = 0;
        #pragma unroll
        for (int r = 0; r < RED; ++r) x += part[(size_t)(b * RED + r) * NBINS + f];
        tot[f] = x;                                // suffix count >= bin f
    }
    __syncthreads();
    u32 tv = tot[0];                               // total valid keys (block-uniform)
    u32 target = (tv < K_PRE) ? tv : K_PRE;
    if (target == 0) {                             // no candidates in this batch
        if (c == 0 && tid == 0) cnt[b] = 0;
        return;
    }
    for (int f = tid; f < NBINS; f += 256) {       // tot non-increasing -> unique crossing
        u32 cge = tot[f];
        u32 cnx = (f + 1 < NBINS) ? tot[f + 1] : 0u;
        if (cge >= target && cnx < target) sTf = (u32)f;
    }
    __syncthreads();
    u32 Tf = sTf;
    if (c == 0 && tid == 0) cnt[b] = tot[Tf];      // batch candidate total (== old scanoff cnt)
    // own exclusive offset: sum of per-slice suffix counts for slices < c
    u32 m = 0;
    if (tid < c) m = bh[(size_t)(b * SB + tid) * NBINS + Tf];
    if (tid + 256 < c) m += bh[(size_t)(b * SB + tid + 256) * NBINS + Tf];
    #pragma unroll
    for (int o = 32; o > 0; o >>= 1) m += __shfl_down(m, o);
    if (lane == 0) wtot[wv] = m;
    __syncthreads();
    u32 boffc = wtot[0] + wtot[1] + wtot[2] + wtot[3];
    __syncthreads();                               // wtot reused by scan below
    // candidate flags + block scan + write
    u32 T16 = BIN0 + Tf;
    int a0 = c * CH2 + tid * 4;
    uint4 kk = make_uint4(0u, 0u, 0u, 0u);
    if (a0 < NN) kk = *((const uint4*)(key + (size_t)b * NN + a0));
    u32 ks[4] = {kk.x, kk.y, kk.z, kk.w};
    u32 f4[4];
    #pragma unroll
    for (int e = 0; e < 4; ++e) f4[e] = (u32)((ks[e] != 0) && ((ks[e] >> 16) >= T16));
    u32 tc = f4[0] + f4[1] + f4[2] + f4[3];
    u32 x = tc;
    #pragma unroll
    for (int o = 1; o < 64; o <<= 1) {
        u32 y = __shfl_up(x, o);
        if (lane >= o) x += y;
    }
    if (lane == 63) wtot[wv] = x;
    __syncthreads();
    u32 base = 0;
    { u32 w0 = wtot[0], w1 = wtot[1], w2 = wtot[2];
      if (wv > 0) base += w0; if (wv > 1) base += w1; if (wv > 2) base += w2; }
    u32 pos = boffc + base + x - tc;
    u64* cb = cand + (size_t)b * CAP;
    #pragma unroll
    for (int e = 0; e < 4; ++e) {
        if (f4[e]) {
            if (pos < CAP) cb[pos] = ((u64)(~ks[e]) << 32) | (u64)(a0 + e);
            ++pos;
        }
    }
}

// ---------------- K4: rank (dense permutation, keys unique) + decode fused ----------------
__global__ __launch_bounds__(256) void k_rankdec(const u32* __restrict__ cnt, const u64* __restrict__ cand,
                                                 const float* __restrict__ boxp, const float* __restrict__ cls,
                                                 const float* __restrict__ dirp, const float* __restrict__ anch,
                                                 float* __restrict__ tks, u32* __restrict__ meta,
                                                 float* __restrict__ box7, float* __restrict__ cor) {
    __shared__ u64 ck[CAP];                       // 32 KB
    int blk = blockIdx.x, tid = threadIdx.x;      // grid = BB*16
    int b = blk >> 4, rb = blk & 15;
    u32 nc = cnt[b]; if (nc > CAP) nc = CAP;
    int ci = rb * 256 + tid;
    if (rb * 256 >= (int)nc && rb * 256 >= K_PRE) return;   // nothing for this block
    const u64* cb = cand + (size_t)b * CAP;
    for (int i = tid; i < (int)nc; i += 256) ck[i] = cb[i];
    __syncthreads();

    int rank = -1; u32 idx = 0xFFFFFFFFu;
    if (ci < (int)nc) {
        u64 my = ck[ci];
        u32 r = 0;
        // explicit 16-wide batches: 16 independent LDS reads in flight per batch
        int j = 0;
        int nlim = (int)nc & ~15;
        for (; j < nlim; j += 16) {
            u64 v0 = ck[j+0], v1 = ck[j+1], v2 = ck[j+2], v3 = ck[j+3];
            u64 v4 = ck[j+4], v5 = ck[j+5], v6 = ck[j+6], v7 = ck[j+7];
            u64 v8 = ck[j+8], v9 = ck[j+9], va = ck[j+10], vb = ck[j+11];
            u64 vc = ck[j+12], vd = ck[j+13], ve = ck[j+14], vf = ck[j+15];
            r += (u32)(v0 < my) + (u32)(v1 < my) + (u32)(v2 < my) + (u32)(v3 < my)
               + (u32)(v4 < my) + (u32)(v5 < my) + (u32)(v6 < my) + (u32)(v7 < my)
               + (u32)(v8 < my) + (u32)(v9 < my) + (u32)(va < my) + (u32)(vb < my)
               + (u32)(vc < my) + (u32)(vd < my) + (u32)(ve < my) + (u32)(vf < my);
        }
        for (; j < (int)nc; ++j) r += (u32)(ck[j] < my);
        if (r < K_PRE) { rank = (int)r; idx = (u32)my; }
    } else if (ci < K_PRE) {
        rank = ci;                                 // invalid-slot filler (disjoint from real ranks)
    }
    if (rank < 0) return;

    float ob[7] = {0,0,0,0,0,0,0};
    float c5[5] = {0,0,0,0,0};
    float sc = 0.f; u32 mt = 0;
    if (idx != 0xFFFFFFFFu) {
        const float* A = anch + (size_t)idx * 7;
        const float* D = boxp + ((size_t)b * NN + idx) * 7;
        float xa=A[0], ya=A[1], za=A[2], wa=A[3], la=A[4], ha=A[5], ra=A[6];
        float xt=D[0], yt=D[1], zt=D[2], wt=D[3], lt=D[4], ht=D[5], rt=D[6];
        za = za + ha * 0.5f;
        float diag = sqrtf(la * la + wa * wa);
        float xg = xt * diag + xa;
        float yg = yt * diag + ya;
        float zg = zt * ha + za;
        float wg = expf(wt) * wa;
        float lg = expf(lt) * la;
        float hg = expf(ht) * ha;
        zg = zg - hg * 0.5f;
        float rg = rt + ra;
        ob[0]=xg; ob[1]=yg; ob[2]=zg; ob[3]=wg; ob[4]=lg; ob[5]=hg; ob[6]=rg;
        float cr = fabsf(cosf(rg)), sr = fabsf(sinf(rg));
        float hx = 0.5f * (wg * cr + lg * sr);
        float hy = 0.5f * (wg * sr + lg * cr);
        float x1 = xg - hx, x2 = xg + hx, y1 = yg - hy, y2 = yg + hy;
        c5[0]=x1; c5[1]=x2; c5[2]=y1; c5[3]=y2; c5[4]=(x2-x1)*(y2-y1);
        const float* cc = cls + ((size_t)b * NN + idx) * 3;
        float p0 = sigm(cc[0]), p1 = sigm(cc[1]), p2 = sigm(cc[2]);
        int lbl = 0; float best = p0;
        if (p1 > best) { best = p1; lbl = 1; }
        if (p2 > best) { best = p2; lbl = 2; }
        sc = best;
        const float* dd = dirp + ((size_t)b * NN + idx) * 2;
        int dl = (dd[1] > dd[0]) ? 1 : 0;
        mt = (u32)lbl | ((u32)dl << 8) | (1u << 16);
    }
    size_t t = (size_t)b * K_PRE + rank;
    tks[t] = sc; meta[t] = mt;
    #pragma unroll
    for (int j = 0; j < 7; ++j) box7[t * 7 + j] = ob[j];
    #pragma unroll
    for (int j = 0; j < 5; ++j) cor[t * 5 + j] = c5[j];
}

// ---------------- K5: TRANSPOSED suppression bitmask (LDS-staged boxes) ----------------
// maskT[j][w] bit ii: box i=w*64+ii suppresses j (i<j && iou>thr)
__global__ __launch_bounds__(256) void k_maskT(const float* __restrict__ cor, u64* __restrict__ maskT) {
    __shared__ float s4[(K_PRE + 16) * 4];        // x1,x2,y1,y2; index i+(i>>6) breaks bank conflicts
    __shared__ float sA[K_PRE + 16];              // area
    int blk = blockIdx.x;                         // grid = BB * 63
    int b = blk / 63, jb = blk % 63;
    int tid = threadIdx.x;
    const float4* C4 = (const float4*)(cor + (size_t)b * K_PRE * 5);
    for (int q = tid; q < (K_PRE * 5) / 4; q += 256) {
        float4 v = C4[q];
        int t0 = q * 4;
        #pragma unroll
        for (int e = 0; e < 4; ++e) {
            int t = t0 + e;
            int i = t / 5, k = t - i * 5;
            float val = (e == 0) ? v.x : (e == 1) ? v.y : (e == 2) ? v.z : v.w;
            int ip = i + (i >> 6);
            if (k < 4) s4[ip * 4 + k] = val; else sA[ip] = val;
        }
    }
    __syncthreads();
    int w = tid & 15, jl = tid >> 4;
    int j = jb * 16 + jl;
    if (j >= K_PRE) return;
    int jp = j + (j >> 6);
    float x1 = s4[jp*4+0], x2 = s4[jp*4+1], y1 = s4[jp*4+2], y2 = s4[jp*4+3], ar = sA[jp];
    u64 m = 0;
    int i0 = w * 64;
    if (i0 < j) {
        int iend = j - i0; if (iend > 64) iend = 64;
        for (int ii = 0; ii < iend; ++ii) {
            int i = i0 + ii;
            int ip = i + (i >> 6);
            float4 bx = *(const float4*)&s4[ip * 4];
            float ai = sA[ip];
            float ix = fminf(x2, bx.y) - fmaxf(x1, bx.x); ix = fmaxf(ix, 0.f);
            float iy = fminf(y2, bx.w) - fmaxf(y1, bx.z); iy = fmaxf(iy, 0.f);
            float inter = ix * iy;
            float uni = ai + ar - inter;              // fp-add commutative == ref order
            float iou = (uni > 0.f) ? inter / fmaxf(uni, 1e-12f) : 0.f;
            if (iou > IOU_THR) m |= (1ull << ii);
        }
    }
    maskT[((size_t)b * K_PRE + j) * NW + w] = m;
}

// ---------------- K6: greedy NMS, register-serial over KEPT boxes only ----------------
__global__ __launch_bounds__(256) void k_nms_out(const u32* __restrict__ meta, const float* __restrict__ box7,
                                                 const float* __restrict__ tks, const u64* __restrict__ maskT,
                                                 float* __restrict__ out) {
    int b = blockIdx.x; int tid = threadIdx.x;
    __shared__ u64 km_s[16];                      // kept-bits per chunk
    __shared__ int sel_s[K_POST];
    __shared__ int cnt_s;
    if (tid < 16) km_s[tid] = 0ull;
    __syncthreads();
    if (tid < 64) {
        int lane = tid;
        const u32* M = meta + b * K_PRE;
        int cnt = 0; bool done = false;
        for (int c = 0; c < 16; ++c) {            // 16 chunks of 64 candidates
            if (done) break;
            int j = c * 64 + lane;
            int jc = (j < K_PRE) ? j : (K_PRE - 1);
            bool jvalid = (j < K_PRE) && ((M[jc] >> 16) & 1u);
            const u64* colp = maskT + ((size_t)b * K_PRE + jc) * NW;
            u64 cw = 0; u64 supacc = 0;
            #pragma unroll
            for (int w = 0; w < 16; ++w) {        // static indices; km_s[w]=0 for w>=c
                u64 cv = colp[w];
                supacc |= (cv & km_s[w]);
                if (w == c) cw = cv;
            }
            u64 active = __ballot(jvalid && (supacc == 0ull));
            u64 kmc = 0;
            while (active) {
                int i = __ffsll((unsigned long long)active) - 1;   // next kept
                if (lane == 0) sel_s[cnt] = c * 64 + i;
                ++cnt;
                if (cnt >= K_POST) { done = true; break; }
                kmc |= (1ull << i);
                u64 supb = __ballot(((cw >> i) & 1ull) != 0ull);   // i suppresses my j?
                active &= ~supb;
                active &= ~(1ull << i);
            }
            if (lane == 0) km_s[c] = kmc;
        }
        if (lane == 0) cnt_s = cnt;
    }
    __syncthreads();
    int cnt = cnt_s;
    const u32* M = meta + b * K_PRE;
    const float* BX = box7 + (size_t)b * K_PRE * 7;
    const float* SS = tks + b * K_PRE;
    for (int p = tid; p < K_POST; p += 256) {
        float ob[7] = {0,0,0,0,0,0,0};
        float sc = 0.f, lb = 0.f, vd = 0.f;
        if (p < cnt) {
            int i = sel_s[p];
            float xg = BX[i*7+0], yg = BX[i*7+1], zg = BX[i*7+2];
            bool in_range = (xg >= 0.0f) && (xg <= 69.12f) &&
                            (yg >= -39.68f) && (yg <= 39.68f) &&
                            (zg >= -5.0f) && (zg <= 5.0f);
            if (in_range) {
                u32 mt = M[i];
                int dl = (mt >> 8) & 0xFF;
                float r = BX[i*7+6];
                bool opp = ((r > 0.0f) != (dl == 1));
                float rf = r + (opp ? 3.14159274f : 0.0f);
                ob[0]=xg; ob[1]=yg; ob[2]=zg; ob[3]=BX[i*7+3]; ob[4]=BX[i*7+4]; ob[5]=BX[i*7+5]; ob[6]=rf;
                sc = SS[i]; lb = (float)(mt & 0xFF); vd = 1.0f;
            }
        }
        size_t ro = (size_t)(b * K_POST + p);
        #pragma unroll
        for (int j = 0; j < 7; ++j) out[ro * 7 + j] = ob[j];
        out[(size_t)BB * K_POST * 7 + ro] = lb;   // labels (as float values)
        out[(size_t)BB * K_POST * 8 + ro] = sc;   // scores
        out[(size_t)BB * K_POST * 9 + ro] = vd;   // valid (0/1)
    }
}

extern "C" void kernel_launch(void* const* d_in, const int* in_sizes, int n_in,
                              void* d_out, int out_size, void* d_ws, size_t ws_size,
                              hipStream_t stream) {
    const float* boxp = (const float*)d_in[0];
    const float* cls  = (const float*)d_in[1];
    const float* dirp = (const float*)d_in[2];
    const float* anch = (const float*)d_in[3];
    float* out = (float*)d_out;

    char* p = (char*)d_ws;
    u32* key  = (u32*)p; p += (size_t)BB * NN * 4;
    u32* bh   = (u32*)p; p += (size_t)BB * SB * NBINS * 4;   // suffix-hist slices
    u32* part = (u32*)p; p += (size_t)BB * RED * NBINS * 4;  // column-sum partials
    u32* cnt  = (u32*)p; p += 256;
    u64* cand = (u64*)p; p += (size_t)BB * CAP * 8;
    float* tks = (float*)p; p += (size_t)BB * K_PRE * 4;
    u32* meta = (u32*)p; p += (size_t)BB * K_PRE * 4;
    float* box7 = (float*)p; p += (size_t)BB * K_PRE * 7 * 4;
    float* cor  = (float*)p; p += (size_t)BB * K_PRE * 5 * 4;
    u64* maskT = (u64*)p; p += (size_t)BB * K_PRE * NW * 8;

    k_score_hist<<<BB * SB, 256, 0, stream>>>(cls, key, bh);
    k_red<<<BB * RED * 9, 64, 0, stream>>>(bh, part);
    k_scatterT<<<BB * SB, 256, 0, stream>>>(key, part, bh, cnt, cand);
    k_rankdec<<<BB * 16, 256, 0, stream>>>(cnt, cand, boxp, cls, dirp, anch, tks, meta, box7, cor);
    k_maskT<<<BB * 63, 256, 0, stream>>>(cor, maskT);
    k_nms_out<<<BB, 256, 0, stream>>>(meta, box7, tks, maskT, out);
}